// Round 10
// baseline (185.379 us; speedup 1.0000x reference)
//
#include <hip/hip_runtime.h>
#include <math.h>

#define NHEADS 8
#define DHEAD 64
#define NDIM 512
#define NFREQ 32
#define POSD 130           // 2*(32*2+1)
#define NB 2
#define NL 272
#define NLS 256
#define NROWS (NB*NL)      // 544
#define ATTN_SCALE 0.125f
#define PHYS_SCALE 51.5f
#define PI_F 3.14159265358979323846f
#define USTR 168           // u_s row stride (shorts)
#define PSTR 72            // p_bf row stride (shorts)

typedef short s16x8 __attribute__((ext_vector_type(8)));
typedef float f32x4 __attribute__((ext_vector_type(4)));

__device__ __forceinline__ short bfb(float x) {
  unsigned short u = __builtin_bit_cast(unsigned short, (__bf16)x);
  return (short)u;
}

// ---------------------------------------------------------------------------
// K1: qkv = x @ [Wq | Wk[:512] | Wv[:512]]   (M=544, N=1536, K=512, fp32)
// ---------------------------------------------------------------------------
__global__ __launch_bounds__(256) void qkv_gemm_k(
    const float* __restrict__ x,
    const float* __restrict__ Wq, const float* __restrict__ Wk,
    const float* __restrict__ Wv,
    float* __restrict__ qkv)
{
  __shared__ float As[16][68];
  __shared__ float Bs[16][64];
  const int t  = threadIdx.x;
  const int m0 = blockIdx.x * 64;
  const int ng = blockIdx.y * 64;
  const int region = ng >> 9;
  const int n0 = ng & 511;
  const float* W = (region == 0) ? Wq : (region == 1) ? Wk : Wv;
  float* out = qkv + (size_t)region * (NROWS * NDIM);

  const int tx = t & 15, ty = t >> 4;
  const int arow = t >> 2, akq = (t & 3) * 4;
  const int brow = t >> 4, bcol = (t & 15) * 4;

  float acc[4][4];
#pragma unroll
  for (int i = 0; i < 4; ++i)
#pragma unroll
    for (int j = 0; j < 4; ++j) acc[i][j] = 0.f;

  for (int k0 = 0; k0 < 512; k0 += 16) {
    float4 av = make_float4(0.f, 0.f, 0.f, 0.f);
    if (m0 + arow < NROWS)
      av = *(const float4*)&x[(size_t)(m0 + arow) * NDIM + k0 + akq];
    As[akq + 0][arow] = av.x; As[akq + 1][arow] = av.y;
    As[akq + 2][arow] = av.z; As[akq + 3][arow] = av.w;
    *(float4*)&Bs[brow][bcol] =
        *(const float4*)&W[(size_t)(k0 + brow) * NDIM + n0 + bcol];
    __syncthreads();
#pragma unroll
    for (int kk = 0; kk < 16; ++kk) {
      float4 a = *(const float4*)&As[kk][ty * 4];
      float4 b = *(const float4*)&Bs[kk][tx * 4];
      float aa[4] = {a.x, a.y, a.z, a.w};
      float bb[4] = {b.x, b.y, b.z, b.w};
#pragma unroll
      for (int i = 0; i < 4; ++i)
#pragma unroll
        for (int j = 0; j < 4; ++j) acc[i][j] = fmaf(aa[i], bb[j], acc[i][j]);
    }
    __syncthreads();
  }
#pragma unroll
  for (int i = 0; i < 4; ++i) {
    int row = m0 + ty * 4 + i;
    if (row < NROWS)
      *(float4*)&out[(size_t)row * NDIM + n0 + tx * 4] =
          make_float4(acc[i][0], acc[i][1], acc[i][2], acc[i][3]);
  }
}

// ---------------------------------------------------------------------------
// K3: out = attn_out @ Wo + bo
// ---------------------------------------------------------------------------
__global__ __launch_bounds__(256) void out_gemm_k(
    const float* __restrict__ A, const float* __restrict__ Wo,
    const float* __restrict__ bo, float* __restrict__ out)
{
  __shared__ float As[16][68];
  __shared__ float Bs[16][64];
  const int t  = threadIdx.x;
  const int m0 = blockIdx.x * 64;
  const int n0 = blockIdx.y * 64;

  const int tx = t & 15, ty = t >> 4;
  const int arow = t >> 2, akq = (t & 3) * 4;
  const int brow = t >> 4, bcol = (t & 15) * 4;

  float acc[4][4];
#pragma unroll
  for (int i = 0; i < 4; ++i)
#pragma unroll
    for (int j = 0; j < 4; ++j) acc[i][j] = 0.f;

  for (int k0 = 0; k0 < 512; k0 += 16) {
    float4 av = make_float4(0.f, 0.f, 0.f, 0.f);
    if (m0 + arow < NROWS)
      av = *(const float4*)&A[(size_t)(m0 + arow) * NDIM + k0 + akq];
    As[akq + 0][arow] = av.x; As[akq + 1][arow] = av.y;
    As[akq + 2][arow] = av.z; As[akq + 3][arow] = av.w;
    *(float4*)&Bs[brow][bcol] =
        *(const float4*)&Wo[(size_t)(k0 + brow) * NDIM + n0 + bcol];
    __syncthreads();
#pragma unroll
    for (int kk = 0; kk < 16; ++kk) {
      float4 a = *(const float4*)&As[kk][ty * 4];
      float4 b = *(const float4*)&Bs[kk][tx * 4];
      float aa[4] = {a.x, a.y, a.z, a.w};
      float bb[4] = {b.x, b.y, b.z, b.w};
#pragma unroll
      for (int i = 0; i < 4; ++i)
#pragma unroll
        for (int j = 0; j < 4; ++j) acc[i][j] = fmaf(aa[i], bb[j], acc[i][j]);
    }
    __syncthreads();
  }
  float4 bv = *(const float4*)&bo[n0 + tx * 4];
  float bb[4] = {bv.x, bv.y, bv.z, bv.w};
#pragma unroll
  for (int i = 0; i < 4; ++i) {
    int row = m0 + ty * 4 + i;
    if (row < NROWS)
      *(float4*)&out[(size_t)row * NDIM + n0 + tx * 4] =
          make_float4(acc[i][0] + bb[0], acc[i][1] + bb[1],
                      acc[i][2] + bb[2], acc[i][3] + bb[3]);
  }
}

// ---------------------------------------------------------------------------
// K2: dual-stream MFMA attention. One block (512 thr, 8 waves) per query row.
// Stream st = t>>8: st 0 -> key tiles 0,1 + 16 global keys; st 1 -> tiles 2,3.
// Each stream keeps its own online-softmax state; merged in the epilogue.
// Permuted pe slot layout (u, w, Wv_pe rows alike):
//   slot 0..31 sin(rc*f*pi) | 32..63 cos(rc*f*pi) | 64..95 sin(th*f*pi)
//   | 96..127 cos(th*f*pi) | 128 rc | 129 th | 130..159 zero
// Fragment maps (gfx950): A m=lane&15 k=(lane>>4)*8+j; B n=lane&15 same k;
// D col=lane&15 row=(lane>>4)*4+reg.
// ---------------------------------------------------------------------------
__global__ __launch_bounds__(512) void attn_mfma_k(
    const float* __restrict__ qb, const float* __restrict__ kb,
    const float* __restrict__ vb, const float* __restrict__ pos,
    const float* __restrict__ Wk, const float* __restrict__ Wv,
    const float* __restrict__ freqs, float* __restrict__ attn_out)
{
  __shared__ float q_s[NDIM];
  __shared__ short u_s[16 * USTR];
  __shared__ float frp_s[NFREQ];
  __shared__ float rc_s[NLS], th_s[NLS];
  __shared__ short p_bf[2][16 * PSTR];
  __shared__ float p_s[2][NHEADS][64];
  __shared__ float s_l[2][NHEADS][64];
  __shared__ float s_pe[2][NHEADS][64];
  __shared__ float w_g[2][NHEADS][160];
  __shared__ float o_g[2][512];
  __shared__ float m_s[2][NHEADS], l_s[2][NHEADS], fac_s[2][NHEADS];

  const int row = blockIdx.x;
  const int b = row / NL;
  const int i = row - b * NL;
  const bool spatial = (i < NLS);
  const int t = threadIdx.x;
  const int st = t >> 8;           // stream 0/1
  const int ts = t & 255;          // thread-in-stream
  const int lane = ts & 63;
  const int wv = ts >> 6;          // wave-in-stream 0..3
  const int g = lane >> 4;
  const int lr = lane & 15;
  const int h_o = ts >> 5;
  const int d0 = (ts & 31) * 2;

  // ---- init ----
  for (int idx = t; idx < 16 * USTR / 2; idx += 512) ((int*)u_s)[idx] = 0;
  for (int idx = t; idx < 2 * 16 * PSTR / 2; idx += 512) ((int*)p_bf)[idx] = 0;
  if (t < NFREQ) frp_s[t] = freqs[t] * PI_F;
  q_s[t] = qb[(size_t)row * NDIM + t];
  if (t < 16) { m_s[t >> 3][t & 7] = -1e30f; l_s[t >> 3][t & 7] = 0.f; }
  __syncthreads();

  float px = 0.f, py = 0.f;
  if (spatial) {
    float2 pv = *(const float2*)&pos[(size_t)(b * NLS + i) * 2];
    px = pv.x; py = pv.y;
  }
  // rc/th for all 256 spatial keys (once per block)
  if (spatial && t < NLS) {
    float2 kp = *(const float2*)&pos[(size_t)(b * NLS + t) * 2];
    float dx = kp.x - px, dy = kp.y - py;
    float r = sqrtf(dx * dx + dy * dy + 1e-8f);
    rc_s[t] = r / (PHYS_SCALE + r);
    th_s[t] = atan2f(dy, dx) * (1.0f / PI_F);
  }
  // u[h][slot] = sum_d q[h*64+d] * Wk[512+f(slot)][h*64+d]  (bf16, permuted)
  if (spatial) {
    for (int idx = t; idx < NHEADS * POSD; idx += 512) {
      int h = idx / POSD, f = idx - h * POSD;
      const float* wr = &Wk[(size_t)(512 + f) * NDIM + h * DHEAD];
      const float* qs = &q_s[h * DHEAD];
      float a0 = 0.f, a1 = 0.f;
#pragma unroll
      for (int d = 0; d < 64; d += 8) {
        float4 w0 = *(const float4*)&wr[d];
        float4 w1 = *(const float4*)&wr[d + 4];
        a0 = fmaf(qs[d], w0.x, a0);     a0 = fmaf(qs[d + 1], w0.y, a0);
        a0 = fmaf(qs[d + 2], w0.z, a0); a0 = fmaf(qs[d + 3], w0.w, a0);
        a1 = fmaf(qs[d + 4], w1.x, a1); a1 = fmaf(qs[d + 5], w1.y, a1);
        a1 = fmaf(qs[d + 6], w1.z, a1); a1 = fmaf(qs[d + 7], w1.w, a1);
      }
      int slot = (f < 64) ? f : (f == 64) ? 128 : (f == 129) ? 129 : f - 1;
      u_s[h * USTR + slot] = bfb(a0 + a1);
    }
  }
  __syncthreads();

  float oA0 = 0.f, oA1 = 0.f, oB0 = 0.f, oB1 = 0.f;   // PV accumulators (j parity)
  f32x4 wacc[3];
#pragma unroll
  for (int q = 0; q < 3; ++q) wacc[q] = (f32x4){0.f, 0.f, 0.f, 0.f};

  // ---- main loop: each stream does 2 tiles ----
  for (int ti = 0; ti < 2; ++ti) {
    const int kbase = (st * 2 + ti) * 64;

    // P1: QK logits (2 per thread, 4 accumulators)
    {
      const int h = ts >> 5, jj = ts & 31;
      const float* qs = &q_s[h * DHEAD];
#pragma unroll
      for (int rep = 0; rep < 2; ++rep) {
        const int j = jj + rep * 32;
        const float* kr = &kb[(size_t)(b * NL + kbase + j) * NDIM + h * DHEAD];
        float a0 = 0.f, a1 = 0.f, a2 = 0.f, a3 = 0.f;
#pragma unroll
        for (int d = 0; d < 64; d += 16) {
          float4 k0v = *(const float4*)&kr[d];
          float4 k1v = *(const float4*)&kr[d + 4];
          float4 k2v = *(const float4*)&kr[d + 8];
          float4 k3v = *(const float4*)&kr[d + 12];
          a0 = fmaf(qs[d + 0], k0v.x, a0);  a0 = fmaf(qs[d + 1], k0v.y, a0);
          a0 = fmaf(qs[d + 2], k0v.z, a0);  a0 = fmaf(qs[d + 3], k0v.w, a0);
          a1 = fmaf(qs[d + 4], k1v.x, a1);  a1 = fmaf(qs[d + 5], k1v.y, a1);
          a1 = fmaf(qs[d + 6], k1v.z, a1);  a1 = fmaf(qs[d + 7], k1v.w, a1);
          a2 = fmaf(qs[d + 8], k2v.x, a2);  a2 = fmaf(qs[d + 9], k2v.y, a2);
          a2 = fmaf(qs[d + 10], k2v.z, a2); a2 = fmaf(qs[d + 11], k2v.w, a2);
          a3 = fmaf(qs[d + 12], k3v.x, a3); a3 = fmaf(qs[d + 13], k3v.y, a3);
          a3 = fmaf(qs[d + 14], k3v.z, a3); a3 = fmaf(qs[d + 15], k3v.w, a3);
        }
        s_l[st][h][j] = ((a0 + a1) + (a2 + a3)) * ATTN_SCALE;
      }
    }
    // P2: pe logits via MFMA (same phase as P1 — disjoint shared writes)
    if (spatial) {
      const int keyloc = kbase + wv * 16 + lr;
      const float rc = rc_s[keyloc], th = th_s[keyloc];
      const float* frp = &frp_s[g * 8];
      s16x8 a0, a1, a2, a3, a4;
#pragma unroll
      for (int j = 0; j < 8; ++j) {
        float s1, c1, s2, c2;
        __sincosf(rc * frp[j], &s1, &c1);
        __sincosf(th * frp[j], &s2, &c2);
        a0[j] = bfb(s1); a1[j] = bfb(c1); a2[j] = bfb(s2); a3[j] = bfb(c2);
        a4[j] = 0;
      }
      if (g == 0) { a4[0] = bfb(rc); a4[1] = bfb(th); }
      const short* ur = &u_s[lr * USTR + g * 8];
      f32x4 acc = (f32x4){0.f, 0.f, 0.f, 0.f};
      acc = __builtin_amdgcn_mfma_f32_16x16x32_bf16(a0, *(const s16x8*)(ur), acc, 0, 0, 0);
      acc = __builtin_amdgcn_mfma_f32_16x16x32_bf16(a1, *(const s16x8*)(ur + 32), acc, 0, 0, 0);
      acc = __builtin_amdgcn_mfma_f32_16x16x32_bf16(a2, *(const s16x8*)(ur + 64), acc, 0, 0, 0);
      acc = __builtin_amdgcn_mfma_f32_16x16x32_bf16(a3, *(const s16x8*)(ur + 96), acc, 0, 0, 0);
      acc = __builtin_amdgcn_mfma_f32_16x16x32_bf16(a4, *(const s16x8*)(ur + 128), acc, 0, 0, 0);
      if (lr < NHEADS) {
#pragma unroll
        for (int r = 0; r < 4; ++r)
          s_pe[st][lr][wv * 16 + g * 4 + r] = acc[r] * ATTN_SCALE;
      }
    }
    __syncthreads();

    // P3: online softmax (32 lanes per head, per stream)
    {
      const int h = ts >> 5, ln = ts & 31;
      float v0 = s_l[st][h][ln];
      float v1 = s_l[st][h][ln + 32];
      if (spatial) { v0 += s_pe[st][h][ln]; v1 += s_pe[st][h][ln + 32]; }
      float mx = fmaxf(v0, v1);
#pragma unroll
      for (int off = 16; off > 0; off >>= 1)
        mx = fmaxf(mx, __shfl_xor(mx, off, 32));
      float m_old = m_s[st][h];
      float m_new = fmaxf(m_old, mx);
      float p0 = __expf(v0 - m_new);
      float p1 = __expf(v1 - m_new);
      p_s[st][h][ln] = p0;        p_bf[st][h * PSTR + ln] = bfb(p0);
      p_s[st][h][ln + 32] = p1;   p_bf[st][h * PSTR + ln + 32] = bfb(p1);
      float sum = p0 + p1;
#pragma unroll
      for (int off = 16; off > 0; off >>= 1)
        sum += __shfl_xor(sum, off, 32);
      if (ln == 0) {
        float fac = __expf(m_old - m_new);
        m_s[st][h] = m_new;
        l_s[st][h] = l_s[st][h] * fac + sum;
        fac_s[st][h] = fac;
      }
    }
    __syncthreads();

    // P4: PV (fp32, 2-way j parity)
    {
      float fac = fac_s[st][h_o];
      oA0 *= fac; oA1 *= fac; oB0 *= fac; oB1 *= fac;
      const float* vbase = &vb[(size_t)(b * NL + kbase) * NDIM + h_o * DHEAD + d0];
      const float* pp = p_s[st][h_o];
#pragma unroll 8
      for (int j = 0; j < 64; j += 2) {
        float pa = pp[j], pc = pp[j + 1];
        float2 va = *(const float2*)&vbase[(size_t)j * NDIM];
        float2 vc = *(const float2*)&vbase[(size_t)(j + 1) * NDIM];
        oA0 = fmaf(pa, va.x, oA0); oA1 = fmaf(pa, va.y, oA1);
        oB0 = fmaf(pc, vc.x, oB0); oB1 = fmaf(pc, vc.y, oB1);
      }
    }
    // P5: w accumulation via MFMA (pe^T[slot x key] @ p[key x head])
    if (spatial) {
      const float facw = fac_s[st][lr & 7];
#pragma unroll
      for (int q = 0; q < 3; ++q) {
        const int mc = wv + q * 4;
        if (mc < 10) {
#pragma unroll
          for (int r = 0; r < 4; ++r) wacc[q][r] *= facw;
          const int s = mc * 16 + lr;
          const float Fp = frp_s[s & 31];
          const bool useTh = (s >= 64 && s < 128) || (s == 129);
          const bool useCos = (s & 32) != 0;
#pragma unroll
          for (int kc = 0; kc < 2; ++kc) {
            s16x8 a;
#pragma unroll
            for (int jj = 0; jj < 8; ++jj) {
              const int j = kbase + kc * 32 + g * 8 + jj;
              float x = useTh ? th_s[j] : rc_s[j];
              float v;
              if (s < 128) {
                float sn, cs;
                __sincosf(x * Fp, &sn, &cs);
                v = useCos ? cs : sn;
              } else {
                v = (s < 130) ? x : 0.f;
              }
              a[jj] = bfb(v);
            }
            const s16x8 pb = *(const s16x8*)&p_bf[st][lr * PSTR + kc * 32 + g * 8];
            wacc[q] = __builtin_amdgcn_mfma_f32_16x16x32_bf16(a, pb, wacc[q], 0, 0, 0);
          }
        }
      }
    }
    __syncthreads();
  }

  // ---- tail: stream 0 handles the 16 global keys (no pe) ----
  {
    if (st == 0) {
      const int h = ts >> 5, j = ts & 31;
      if (j < 16) {
        const float* kr = &kb[(size_t)(b * NL + 256 + j) * NDIM + h * DHEAD];
        const float* qs = &q_s[h * DHEAD];
        float a0 = 0.f, a1 = 0.f;
#pragma unroll
        for (int d = 0; d < 64; d += 8) {
          float4 k0v = *(const float4*)&kr[d];
          float4 k1v = *(const float4*)&kr[d + 4];
          a0 = fmaf(qs[d], k0v.x, a0);     a0 = fmaf(qs[d + 1], k0v.y, a0);
          a0 = fmaf(qs[d + 2], k0v.z, a0); a0 = fmaf(qs[d + 3], k0v.w, a0);
          a1 = fmaf(qs[d + 4], k1v.x, a1); a1 = fmaf(qs[d + 5], k1v.y, a1);
          a1 = fmaf(qs[d + 6], k1v.z, a1); a1 = fmaf(qs[d + 7], k1v.w, a1);
        }
        s_l[0][h][j] = (a0 + a1) * ATTN_SCALE;
      }
    }
    __syncthreads();
    if (st == 0) {
      const int h = ts >> 5, ln = ts & 31;
      float v = (ln < 16) ? s_l[0][h][ln] : -1e30f;
      float mx = v;
#pragma unroll
      for (int off = 16; off > 0; off >>= 1)
        mx = fmaxf(mx, __shfl_xor(mx, off, 32));
      float m_old = m_s[0][h];
      float m_new = fmaxf(m_old, mx);
      float p = (ln < 16) ? __expf(v - m_new) : 0.f;
      if (ln < 16) p_s[0][h][ln] = p;
      float sum = p;
#pragma unroll
      for (int off = 16; off > 0; off >>= 1)
        sum += __shfl_xor(sum, off, 32);
      if (ln == 0) {
        float fac = __expf(m_old - m_new);
        m_s[0][h] = m_new;
        l_s[0][h] = l_s[0][h] * fac + sum;
        fac_s[0][h] = fac;
      }
    }
    __syncthreads();
    if (st == 0) {
      float fac = fac_s[0][h_o];
      oA0 *= fac; oA1 *= fac; oB0 *= fac; oB1 *= fac;
      const float* vbase = &vb[(size_t)(b * NL + 256) * NDIM + h_o * DHEAD + d0];
      const float* pp = p_s[0][h_o];
#pragma unroll 4
      for (int j = 0; j < 16; j += 2) {
        float pa = pp[j], pc = pp[j + 1];
        float2 va = *(const float2*)&vbase[(size_t)j * NDIM];
        float2 vc = *(const float2*)&vbase[(size_t)(j + 1) * NDIM];
        oA0 = fmaf(pa, va.x, oA0); oA1 = fmaf(pa, va.y, oA1);
        oB0 = fmaf(pc, vc.x, oB0); oB1 = fmaf(pc, vc.y, oB1);
      }
      if (spatial) {
        const float facw = fac_s[0][lr & 7];
#pragma unroll
        for (int q = 0; q < 3; ++q)
#pragma unroll
          for (int r = 0; r < 4; ++r) wacc[q][r] *= facw;
      }
    }
  }

  // ---- epilogue: publish per-stream partials ----
  o_g[st][h_o * 64 + d0] = oA0 + oB0;
  o_g[st][h_o * 64 + d0 + 1] = oA1 + oB1;
  if (spatial && lr < NHEADS) {
#pragma unroll
    for (int q = 0; q < 3; ++q) {
      const int mc = wv + q * 4;
      if (mc < 10) {
#pragma unroll
        for (int r = 0; r < 4; ++r)
          w_g[st][lr][mc * 16 + g * 4 + r] = wacc[q][r];
      }
    }
  }
  __syncthreads();

  // ---- combine streams + Wv_pe projection (1 element per thread) ----
  {
    const int h = t >> 6, dd = t & 63;
    float mA = m_s[0][h], mB = m_s[1][h];
    float M = fmaxf(mA, mB);
    float fA = __expf(mA - M), fB = __expf(mB - M);
    float L = l_s[0][h] * fA + l_s[1][h] * fB;
    float oc = o_g[0][t] * fA + o_g[1][t] * fB;
    if (spatial) {
      const float* wA = w_g[0][h];
      const float* wB = w_g[1][h];
      const float* wvb = &Wv[(size_t)512 * NDIM + h * DHEAD + dd];
#pragma unroll 4
      for (int sf = 0; sf < 64; ++sf) {
        float wc = wA[sf] * fA + wB[sf] * fB;
        oc = fmaf(wc, wvb[(size_t)sf * NDIM], oc);
      }
#pragma unroll 4
      for (int sf = 64; sf < 128; ++sf) {
        float wc = wA[sf] * fA + wB[sf] * fB;
        oc = fmaf(wc, wvb[(size_t)(sf + 1) * NDIM], oc);
      }
      {
        float wc = wA[128] * fA + wB[128] * fB;
        oc = fmaf(wc, wvb[(size_t)64 * NDIM], oc);
        wc = wA[129] * fA + wB[129] * fB;
        oc = fmaf(wc, wvb[(size_t)129 * NDIM], oc);
      }
    }
    attn_out[(size_t)row * NDIM + t] = oc / L;
  }
}

// ---------------------------------------------------------------------------
extern "C" void kernel_launch(void* const* d_in, const int* in_sizes, int n_in,
                              void* d_out, int out_size, void* d_ws, size_t ws_size,
                              hipStream_t stream)
{
  (void)in_sizes; (void)n_in; (void)out_size; (void)ws_size;
  const float* x     = (const float*)d_in[0];
  const float* pos   = (const float*)d_in[1];
  const float* Wq    = (const float*)d_in[2];
  const float* Wk    = (const float*)d_in[3];
  const float* Wv    = (const float*)d_in[4];
  const float* Wo    = (const float*)d_in[5];
  const float* bo    = (const float*)d_in[6];
  const float* freqs = (const float*)d_in[7];

  float* ws = (float*)d_ws;
  float* qkv = ws;                                   // [3][544][512]
  float* qb  = qkv;
  float* kb  = qkv + (size_t)NROWS * NDIM;
  float* vb  = qkv + (size_t)2 * NROWS * NDIM;
  float* ao  = qkv + (size_t)3 * NROWS * NDIM;       // [544][512]

  qkv_gemm_k<<<dim3((NROWS + 63) / 64, 24), 256, 0, stream>>>(x, Wq, Wk, Wv, qkv);
  attn_mfma_k<<<dim3(NROWS), 512, 0, stream>>>(qb, kb, vb, pos, Wk, Wv, freqs, ao);
  out_gemm_k<<<dim3((NROWS + 63) / 64, 8), 256, 0, stream>>>(ao, Wo, bo, (float*)d_out);
}

// Round 11
// 178.929 us; speedup vs baseline: 1.0360x; 1.0360x over previous
//
#include <hip/hip_runtime.h>
#include <math.h>

#define NHEADS 8
#define DHEAD 64
#define NDIM 512
#define NFREQ 32
#define POSD 130           // 2*(32*2+1)
#define NB 2
#define NL 272
#define NLS 256
#define NROWS (NB*NL)      // 544
#define ATTN_SCALE 0.125f
#define PHYS_SCALE 51.5f
#define PI_F 3.14159265358979323846f
#define USTR 168           // u_s row stride (shorts)
#define PSTR 72            // p_bf row stride (shorts)
#define PART_STRIDE 264    // 256 o + 4 m + 4 l

typedef short s16x8 __attribute__((ext_vector_type(8)));
typedef float f32x4 __attribute__((ext_vector_type(4)));

__device__ __forceinline__ short bfb(float x) {
  unsigned short u = __builtin_bit_cast(unsigned short, (__bf16)x);
  return (short)u;
}

// ---------------------------------------------------------------------------
// K1: qkv = x @ [Wq | Wk[:512] | Wv[:512]]   (M=544, N=1536, K=512, fp32)
// ---------------------------------------------------------------------------
__global__ __launch_bounds__(256) void qkv_gemm_k(
    const float* __restrict__ x,
    const float* __restrict__ Wq, const float* __restrict__ Wk,
    const float* __restrict__ Wv,
    float* __restrict__ qkv)
{
  __shared__ float As[16][68];
  __shared__ float Bs[16][64];
  const int t  = threadIdx.x;
  const int m0 = blockIdx.x * 64;
  const int ng = blockIdx.y * 64;
  const int region = ng >> 9;
  const int n0 = ng & 511;
  const float* W = (region == 0) ? Wq : (region == 1) ? Wk : Wv;
  float* out = qkv + (size_t)region * (NROWS * NDIM);

  const int tx = t & 15, ty = t >> 4;
  const int arow = t >> 2, akq = (t & 3) * 4;
  const int brow = t >> 4, bcol = (t & 15) * 4;

  float acc[4][4];
#pragma unroll
  for (int i = 0; i < 4; ++i)
#pragma unroll
    for (int j = 0; j < 4; ++j) acc[i][j] = 0.f;

  for (int k0 = 0; k0 < 512; k0 += 16) {
    float4 av = make_float4(0.f, 0.f, 0.f, 0.f);
    if (m0 + arow < NROWS)
      av = *(const float4*)&x[(size_t)(m0 + arow) * NDIM + k0 + akq];
    As[akq + 0][arow] = av.x; As[akq + 1][arow] = av.y;
    As[akq + 2][arow] = av.z; As[akq + 3][arow] = av.w;
    *(float4*)&Bs[brow][bcol] =
        *(const float4*)&W[(size_t)(k0 + brow) * NDIM + n0 + bcol];
    __syncthreads();
#pragma unroll
    for (int kk = 0; kk < 16; ++kk) {
      float4 a = *(const float4*)&As[kk][ty * 4];
      float4 b = *(const float4*)&Bs[kk][tx * 4];
      float aa[4] = {a.x, a.y, a.z, a.w};
      float bb[4] = {b.x, b.y, b.z, b.w};
#pragma unroll
      for (int i = 0; i < 4; ++i)
#pragma unroll
        for (int j = 0; j < 4; ++j) acc[i][j] = fmaf(aa[i], bb[j], acc[i][j]);
    }
    __syncthreads();
  }
#pragma unroll
  for (int i = 0; i < 4; ++i) {
    int row = m0 + ty * 4 + i;
    if (row < NROWS)
      *(float4*)&out[(size_t)row * NDIM + n0 + tx * 4] =
          make_float4(acc[i][0], acc[i][1], acc[i][2], acc[i][3]);
  }
}

// ---------------------------------------------------------------------------
// K4: out = attn_out @ Wo + bo
// ---------------------------------------------------------------------------
__global__ __launch_bounds__(256) void out_gemm_k(
    const float* __restrict__ A, const float* __restrict__ Wo,
    const float* __restrict__ bo, float* __restrict__ out)
{
  __shared__ float As[16][68];
  __shared__ float Bs[16][64];
  const int t  = threadIdx.x;
  const int m0 = blockIdx.x * 64;
  const int n0 = blockIdx.y * 64;

  const int tx = t & 15, ty = t >> 4;
  const int arow = t >> 2, akq = (t & 3) * 4;
  const int brow = t >> 4, bcol = (t & 15) * 4;

  float acc[4][4];
#pragma unroll
  for (int i = 0; i < 4; ++i)
#pragma unroll
    for (int j = 0; j < 4; ++j) acc[i][j] = 0.f;

  for (int k0 = 0; k0 < 512; k0 += 16) {
    float4 av = make_float4(0.f, 0.f, 0.f, 0.f);
    if (m0 + arow < NROWS)
      av = *(const float4*)&A[(size_t)(m0 + arow) * NDIM + k0 + akq];
    As[akq + 0][arow] = av.x; As[akq + 1][arow] = av.y;
    As[akq + 2][arow] = av.z; As[akq + 3][arow] = av.w;
    *(float4*)&Bs[brow][bcol] =
        *(const float4*)&Wo[(size_t)(k0 + brow) * NDIM + n0 + bcol];
    __syncthreads();
#pragma unroll
    for (int kk = 0; kk < 16; ++kk) {
      float4 a = *(const float4*)&As[kk][ty * 4];
      float4 b = *(const float4*)&Bs[kk][tx * 4];
      float aa[4] = {a.x, a.y, a.z, a.w};
      float bb[4] = {b.x, b.y, b.z, b.w};
#pragma unroll
      for (int i = 0; i < 4; ++i)
#pragma unroll
        for (int j = 0; j < 4; ++j) acc[i][j] = fmaf(aa[i], bb[j], acc[i][j]);
    }
    __syncthreads();
  }
  float4 bv = *(const float4*)&bo[n0 + tx * 4];
  float bb[4] = {bv.x, bv.y, bv.z, bv.w};
#pragma unroll
  for (int i = 0; i < 4; ++i) {
    int row = m0 + ty * 4 + i;
    if (row < NROWS)
      *(float4*)&out[(size_t)row * NDIM + n0 + tx * 4] =
          make_float4(acc[i][0] + bb[0], acc[i][1] + bb[1],
                      acc[i][2] + bb[2], acc[i][3] + bb[3]);
  }
}

// ---------------------------------------------------------------------------
// K2: head/key-split MFMA attention. Block = (row, head-group hg, key-split ks).
// hg owns heads hg*4..+3; ks owns key tiles {2ks, 2ks+1}; ks=1 also the 16
// global keys. Writes unnormalized partial (o[256], m[4], l[4]) incl. this
// split's pe contribution via w @ Wv_pe.
// pe slot layout (u, w, Wv_pe rows alike):
//   slot 0..31 sin(rc*f*pi) | 32..63 cos(rc*f*pi) | 64..95 sin(th*f*pi)
//   | 96..127 cos(th*f*pi) | 128 rc | 129 th | 130..159 zero
// Fragment maps (gfx950): A m=lane&15 k=(lane>>4)*8+j; B n=lane&15 same k;
// D col=lane&15 row=(lane>>4)*4+reg.
// ---------------------------------------------------------------------------
__global__ __launch_bounds__(256) void attn_split_k(
    const float* __restrict__ qb, const float* __restrict__ kb,
    const float* __restrict__ vb, const float* __restrict__ pos,
    const float* __restrict__ Wk, const float* __restrict__ Wv,
    const float* __restrict__ freqs, float* __restrict__ part)
{
  __shared__ float q_s[256];          // 4 heads x 64
  __shared__ short u_s[16 * USTR];
  __shared__ short p_bf[16 * PSTR];
  __shared__ float p_s[4][64];
  __shared__ float s_l[4][64];
  __shared__ float s_pe[4][64];
  __shared__ float w_s[4][160];
  __shared__ float rc_s[128], th_s[128];
  __shared__ float frp_s[NFREQ];
  __shared__ float m_s[4], l_s[4], fac_s[4];

  const int row = blockIdx.x;
  const int hg  = blockIdx.y;
  const int ks  = blockIdx.z;
  const int b = row / NL;
  const int i = row - b * NL;
  const bool spatial = (i < NLS);
  const int t = threadIdx.x;
  const int lane = t & 63;
  const int wv = t >> 6;            // wave 0..3
  const int g = lane >> 4;
  const int lr = lane & 15;
  const int hbase = hg * 4;
  const int h4 = t >> 6;            // head-in-group (per-wave)
  const int dd = t & 63;

  for (int idx = t; idx < 16 * USTR / 2; idx += 256) ((int*)u_s)[idx] = 0;
  for (int idx = t; idx < 16 * PSTR / 2; idx += 256) ((int*)p_bf)[idx] = 0;
  if (t < NFREQ) frp_s[t] = freqs[t] * PI_F;
  q_s[t] = qb[(size_t)row * NDIM + hbase * DHEAD + t];
  if (t < 4) { m_s[t] = -1e30f; l_s[t] = 0.f; }
  __syncthreads();

  float px = 0.f, py = 0.f;
  if (spatial) {
    float2 pv = *(const float2*)&pos[(size_t)(b * NLS + i) * 2];
    px = pv.x; py = pv.y;
  }
  // rc/th for this split's 128 spatial keys
  if (spatial && t < 128) {
    int key = ks * 128 + t;
    float2 kp = *(const float2*)&pos[(size_t)(b * NLS + key) * 2];
    float dx = kp.x - px, dy = kp.y - py;
    float r = sqrtf(dx * dx + dy * dy + 1e-8f);
    rc_s[t] = r / (PHYS_SCALE + r);
    th_s[t] = atan2f(dy, dx) * (1.0f / PI_F);
  }
  // u for this head-group: u[hh][slot] = sum_d q[hh*64+d]*Wk[512+f][.]
  if (spatial) {
    for (int idx = t; idx < 4 * POSD; idx += 256) {
      int hh = idx / POSD, f = idx - hh * POSD;
      const float* wr = &Wk[(size_t)(512 + f) * NDIM + (hbase + hh) * DHEAD];
      const float* qs = &q_s[hh * DHEAD];
      float a0 = 0.f, a1 = 0.f;
#pragma unroll
      for (int d = 0; d < 64; d += 8) {
        float4 w0 = *(const float4*)&wr[d];
        float4 w1 = *(const float4*)&wr[d + 4];
        a0 = fmaf(qs[d], w0.x, a0);     a0 = fmaf(qs[d + 1], w0.y, a0);
        a0 = fmaf(qs[d + 2], w0.z, a0); a0 = fmaf(qs[d + 3], w0.w, a0);
        a1 = fmaf(qs[d + 4], w1.x, a1); a1 = fmaf(qs[d + 5], w1.y, a1);
        a1 = fmaf(qs[d + 6], w1.z, a1); a1 = fmaf(qs[d + 7], w1.w, a1);
      }
      int slot = (f < 64) ? f : (f == 64) ? 128 : (f == 129) ? 129 : f - 1;
      u_s[hh * USTR + slot] = bfb(a0 + a1);
    }
  }
  __syncthreads();

  float oA = 0.f, oB = 0.f;
  f32x4 wacc[3];
#pragma unroll
  for (int q = 0; q < 3; ++q) wacc[q] = (f32x4){0.f, 0.f, 0.f, 0.f};

  // ---- main loop: 2 tiles of 64 keys ----
  for (int ti = 0; ti < 2; ++ti) {
    const int kbase = ks * 128 + ti * 64;
    const int koff = ti * 64;

    // phase A: QK (1 dot/thread) + pe MFMA
    {
      const int j = dd;
      const float* kr = &kb[(size_t)(b * NL + kbase + j) * NDIM + (hbase + h4) * DHEAD];
      const float* qs = &q_s[h4 * DHEAD];
      float a0 = 0.f, a1 = 0.f, a2 = 0.f, a3 = 0.f;
#pragma unroll
      for (int d = 0; d < 64; d += 16) {
        float4 k0v = *(const float4*)&kr[d];
        float4 k1v = *(const float4*)&kr[d + 4];
        float4 k2v = *(const float4*)&kr[d + 8];
        float4 k3v = *(const float4*)&kr[d + 12];
        a0 = fmaf(qs[d + 0], k0v.x, a0);  a0 = fmaf(qs[d + 1], k0v.y, a0);
        a0 = fmaf(qs[d + 2], k0v.z, a0);  a0 = fmaf(qs[d + 3], k0v.w, a0);
        a1 = fmaf(qs[d + 4], k1v.x, a1);  a1 = fmaf(qs[d + 5], k1v.y, a1);
        a1 = fmaf(qs[d + 6], k1v.z, a1);  a1 = fmaf(qs[d + 7], k1v.w, a1);
        a2 = fmaf(qs[d + 8], k2v.x, a2);  a2 = fmaf(qs[d + 9], k2v.y, a2);
        a2 = fmaf(qs[d + 10], k2v.z, a2); a2 = fmaf(qs[d + 11], k2v.w, a2);
        a3 = fmaf(qs[d + 12], k3v.x, a3); a3 = fmaf(qs[d + 13], k3v.y, a3);
        a3 = fmaf(qs[d + 14], k3v.z, a3); a3 = fmaf(qs[d + 15], k3v.w, a3);
      }
      s_l[h4][j] = ((a0 + a1) + (a2 + a3)) * ATTN_SCALE;
    }
    if (spatial) {
      const int keyloc = koff + wv * 16 + lr;
      const float rc = rc_s[keyloc], th = th_s[keyloc];
      const float* frp = &frp_s[g * 8];
      s16x8 a0, a1, a2, a3, a4;
#pragma unroll
      for (int j = 0; j < 8; ++j) {
        float s1, c1, s2, c2;
        __sincosf(rc * frp[j], &s1, &c1);
        __sincosf(th * frp[j], &s2, &c2);
        a0[j] = bfb(s1); a1[j] = bfb(c1); a2[j] = bfb(s2); a3[j] = bfb(c2);
        a4[j] = 0;
      }
      if (g == 0) { a4[0] = bfb(rc); a4[1] = bfb(th); }
      const short* ur = &u_s[lr * USTR + g * 8];
      f32x4 acc = (f32x4){0.f, 0.f, 0.f, 0.f};
      acc = __builtin_amdgcn_mfma_f32_16x16x32_bf16(a0, *(const s16x8*)(ur), acc, 0, 0, 0);
      acc = __builtin_amdgcn_mfma_f32_16x16x32_bf16(a1, *(const s16x8*)(ur + 32), acc, 0, 0, 0);
      acc = __builtin_amdgcn_mfma_f32_16x16x32_bf16(a2, *(const s16x8*)(ur + 64), acc, 0, 0, 0);
      acc = __builtin_amdgcn_mfma_f32_16x16x32_bf16(a3, *(const s16x8*)(ur + 96), acc, 0, 0, 0);
      acc = __builtin_amdgcn_mfma_f32_16x16x32_bf16(a4, *(const s16x8*)(ur + 128), acc, 0, 0, 0);
      if (lr < 4) {
#pragma unroll
        for (int r = 0; r < 4; ++r)
          s_pe[lr][wv * 16 + g * 4 + r] = acc[r] * ATTN_SCALE;
      }
    }
    __syncthreads();

    // phase B: online softmax (wave per head, 64 lanes = 64 keys)
    {
      float v = s_l[h4][dd];
      if (spatial) v += s_pe[h4][dd];
      float mx = v;
#pragma unroll
      for (int off = 32; off > 0; off >>= 1)
        mx = fmaxf(mx, __shfl_xor(mx, off, 64));
      float m_old = m_s[h4];
      float m_new = fmaxf(m_old, mx);
      float p = __expf(v - m_new);
      p_s[h4][dd] = p;
      p_bf[h4 * PSTR + dd] = bfb(p);
      float sum = p;
#pragma unroll
      for (int off = 32; off > 0; off >>= 1)
        sum += __shfl_xor(sum, off, 64);
      if (lane == 0) {
        float fac = __expf(m_old - m_new);
        m_s[h4] = m_new;
        l_s[h4] = l_s[h4] * fac + sum;
        fac_s[h4] = fac;
      }
    }
    __syncthreads();

    // phase C: PV (1 dim/thread) + w-accum MFMA
    {
      float fac = fac_s[h4];
      oA *= fac; oB *= fac;
      const float* vbase = &vb[(size_t)(b * NL + kbase) * NDIM + (hbase + h4) * DHEAD + dd];
      const float* pp = p_s[h4];
#pragma unroll 8
      for (int j = 0; j < 64; j += 2) {
        oA = fmaf(pp[j], vbase[(size_t)j * NDIM], oA);
        oB = fmaf(pp[j + 1], vbase[(size_t)(j + 1) * NDIM], oB);
      }
    }
    if (spatial) {
      const float facw = fac_s[lr & 3];
#pragma unroll
      for (int q = 0; q < 3; ++q) {
        const int mc = wv + q * 4;
        if (mc < 10) {
#pragma unroll
          for (int r = 0; r < 4; ++r) wacc[q][r] *= facw;
          const int s = mc * 16 + lr;
          const float Fp = frp_s[s & 31];
          const bool useTh = (s >= 64 && s < 128) || (s == 129);
          const bool useCos = (s & 32) != 0;
#pragma unroll
          for (int kc = 0; kc < 2; ++kc) {
            s16x8 a;
#pragma unroll
            for (int jj = 0; jj < 8; ++jj) {
              const int j = koff + kc * 32 + g * 8 + jj;
              float x = useTh ? th_s[j] : rc_s[j];
              float v;
              if (s < 128) {
                float sn, cs;
                __sincosf(x * Fp, &sn, &cs);
                v = useCos ? cs : sn;
              } else {
                v = (s < 130) ? x : 0.f;
              }
              a[jj] = bfb(v);
            }
            const s16x8 pb = *(const s16x8*)&p_bf[lr * PSTR + kc * 32 + g * 8];
            wacc[q] = __builtin_amdgcn_mfma_f32_16x16x32_bf16(a, pb, wacc[q], 0, 0, 0);
          }
        }
      }
    }
    __syncthreads();
  }

  // ---- tail (ks==1): 16 global keys, no pe ----
  if (ks == 1) {
    if (t < 64) {
      const int hh = t >> 4, j = t & 15;
      const float* kr = &kb[(size_t)(b * NL + 256 + j) * NDIM + (hbase + hh) * DHEAD];
      const float* qs = &q_s[hh * DHEAD];
      float a0 = 0.f, a1 = 0.f;
#pragma unroll
      for (int d = 0; d < 64; d += 8) {
        float4 k0v = *(const float4*)&kr[d];
        float4 k1v = *(const float4*)&kr[d + 4];
        a0 = fmaf(qs[d], k0v.x, a0);     a0 = fmaf(qs[d + 1], k0v.y, a0);
        a0 = fmaf(qs[d + 2], k0v.z, a0); a0 = fmaf(qs[d + 3], k0v.w, a0);
        a1 = fmaf(qs[d + 4], k1v.x, a1); a1 = fmaf(qs[d + 5], k1v.y, a1);
        a1 = fmaf(qs[d + 6], k1v.z, a1); a1 = fmaf(qs[d + 7], k1v.w, a1);
      }
      s_l[hh][j] = (a0 + a1) * ATTN_SCALE;
    }
    __syncthreads();
    {
      float v = (dd < 16) ? s_l[h4][dd] : -1e30f;
      float mx = v;
#pragma unroll
      for (int off = 32; off > 0; off >>= 1)
        mx = fmaxf(mx, __shfl_xor(mx, off, 64));
      float m_old = m_s[h4];
      float m_new = fmaxf(m_old, mx);
      float p = (dd < 16) ? __expf(v - m_new) : 0.f;
      if (dd < 16) p_s[h4][dd] = p;
      float sum = p;
#pragma unroll
      for (int off = 32; off > 0; off >>= 1)
        sum += __shfl_xor(sum, off, 64);
      if (lane == 0) {
        float fac = __expf(m_old - m_new);
        m_s[h4] = m_new;
        l_s[h4] = l_s[h4] * fac + sum;
        fac_s[h4] = fac;
      }
    }
    __syncthreads();
    {
      float fac = fac_s[h4];
      oA *= fac; oB *= fac;
      const float* vbase = &vb[(size_t)(b * NL + 256) * NDIM + (hbase + h4) * DHEAD + dd];
      const float* pp = p_s[h4];
#pragma unroll 4
      for (int j = 0; j < 16; j += 2) {
        oA = fmaf(pp[j], vbase[(size_t)j * NDIM], oA);
        oB = fmaf(pp[j + 1], vbase[(size_t)(j + 1) * NDIM], oB);
      }
    }
    if (spatial) {
      const float facw = fac_s[lr & 3];
#pragma unroll
      for (int q = 0; q < 3; ++q)
#pragma unroll
        for (int r = 0; r < 4; ++r) wacc[q][r] *= facw;
    }
  }

  // ---- epilogue: gather w, project with Wv_pe, write partial ----
  __syncthreads();
  if (spatial && lr < 4) {
#pragma unroll
    for (int q = 0; q < 3; ++q) {
      const int mc = wv + q * 4;
      if (mc < 10) {
#pragma unroll
        for (int r = 0; r < 4; ++r)
          w_s[lr][mc * 16 + g * 4 + r] = wacc[q][r];
      }
    }
  }
  __syncthreads();

  float o = oA + oB;
  if (spatial) {
    const float* wsr = w_s[h4];
    const float* wvb = &Wv[(size_t)512 * NDIM + (hbase + h4) * DHEAD + dd];
    float e0 = 0.f, e1 = 0.f;
#pragma unroll 4
    for (int sf = 0; sf < 64; sf += 2) {       // slots 0..63 -> rows sf
      e0 = fmaf(wsr[sf], wvb[(size_t)sf * NDIM], e0);
      e1 = fmaf(wsr[sf + 1], wvb[(size_t)(sf + 1) * NDIM], e1);
    }
#pragma unroll 4
    for (int sf = 64; sf < 128; sf += 2) {     // slots 64..127 -> rows sf+1
      e0 = fmaf(wsr[sf], wvb[(size_t)(sf + 1) * NDIM], e0);
      e1 = fmaf(wsr[sf + 1], wvb[(size_t)(sf + 2) * NDIM], e1);
    }
    e0 = fmaf(wsr[128], wvb[(size_t)64 * NDIM], e0);    // slot 128 = rc (row 64)
    e1 = fmaf(wsr[129], wvb[(size_t)129 * NDIM], e1);   // slot 129 = th (row 129)
    o += e0 + e1;
  }
  float* prow = part + ((size_t)(ks * NROWS + row) * 2 + hg) * PART_STRIDE;
  prow[t] = o;
  if (t < 4) { prow[256 + t] = m_s[t]; prow[260 + t] = l_s[t]; }
}

// ---------------------------------------------------------------------------
// K3: combine 2 key-split partials per (row, head-group)
// ---------------------------------------------------------------------------
__global__ __launch_bounds__(256) void combine_k(
    const float* __restrict__ part, float* __restrict__ ao)
{
  const int row = blockIdx.x;
  const int hg = blockIdx.y;
  const int t = threadIdx.x;
  const int h4 = t >> 6;

  const float* p0 = part + ((size_t)(0 * NROWS + row) * 2 + hg) * PART_STRIDE;
  const float* p1 = part + ((size_t)(1 * NROWS + row) * 2 + hg) * PART_STRIDE;
  float m0 = p0[256 + h4], m1 = p1[256 + h4];
  float M = fmaxf(m0, m1);
  float f0 = __expf(m0 - M), f1 = __expf(m1 - M);
  float L = p0[260 + h4] * f0 + p1[260 + h4] * f1;
  ao[(size_t)row * NDIM + hg * 256 + t] = (p0[t] * f0 + p1[t] * f1) / L;
}

// ---------------------------------------------------------------------------
extern "C" void kernel_launch(void* const* d_in, const int* in_sizes, int n_in,
                              void* d_out, int out_size, void* d_ws, size_t ws_size,
                              hipStream_t stream)
{
  (void)in_sizes; (void)n_in; (void)out_size; (void)ws_size;
  const float* x     = (const float*)d_in[0];
  const float* pos   = (const float*)d_in[1];
  const float* Wq    = (const float*)d_in[2];
  const float* Wk    = (const float*)d_in[3];
  const float* Wv    = (const float*)d_in[4];
  const float* Wo    = (const float*)d_in[5];
  const float* bo    = (const float*)d_in[6];
  const float* freqs = (const float*)d_in[7];

  float* ws = (float*)d_ws;
  float* qkv  = ws;                                   // [3][544][512]
  float* qb   = qkv;
  float* kb   = qkv + (size_t)NROWS * NDIM;
  float* vb   = qkv + (size_t)2 * NROWS * NDIM;
  float* ao   = qkv + (size_t)3 * NROWS * NDIM;       // [544][512]
  float* part = ao  + (size_t)NROWS * NDIM;           // [2][544][2][264]

  qkv_gemm_k<<<dim3((NROWS + 63) / 64, 24), 256, 0, stream>>>(x, Wq, Wk, Wv, qkv);
  attn_split_k<<<dim3(NROWS, 2, 2), 256, 0, stream>>>(qb, kb, vb, pos, Wk, Wv, freqs, part);
  combine_k<<<dim3(NROWS, 2), 256, 0, stream>>>(part, ao);
  out_gemm_k<<<dim3((NROWS + 63) / 64, 8), 256, 0, stream>>>(ao, Wo, bo, (float*)d_out);
}

// Round 23
// 124.251 us; speedup vs baseline: 1.4920x; 1.4401x over previous
//
#include <hip/hip_runtime.h>
#include <math.h>

#define NHEADS 8
#define DHEAD 64
#define NDIM 512
#define NFREQ 32
#define POSD 130           // 2*(32*2+1)
#define NB 2
#define NL 272
#define NLS 256
#define NROWS (NB*NL)      // 544
#define ATTN_SCALE 0.125f
#define PHYS_SCALE 51.5f
#define PI_F 3.14159265358979323846f
#define USTR 168           // u_s row stride (shorts)
#define PSTR 72            // p_bf row stride (shorts)
#define PART_STRIDE 264    // 256 o + 4 m + 4 l
#define SROWS 320          // padded rows per (head,batch)
#define SCOLS 320          // padded key cols
#define UCOLS 132

typedef short s16x8 __attribute__((ext_vector_type(8)));
typedef float f32x4 __attribute__((ext_vector_type(4)));

__device__ __forceinline__ short bfb(float x) {
  unsigned short u = __builtin_bit_cast(unsigned short, (__bf16)x);
  return (short)u;
}

// ---------------------------------------------------------------------------
// K1: qkv = x @ [Wq | Wk[:512] | Wv[:512]]   (M=544, N=1536, K=512, fp32)
// ---------------------------------------------------------------------------
__global__ __launch_bounds__(256) void qkv_gemm_k(
    const float* __restrict__ x,
    const float* __restrict__ Wq, const float* __restrict__ Wk,
    const float* __restrict__ Wv,
    float* __restrict__ qkv)
{
  __shared__ float As[16][68];
  __shared__ float Bs[16][64];
  const int t  = threadIdx.x;
  const int m0 = blockIdx.x * 64;
  const int ng = blockIdx.y * 64;
  const int region = ng >> 9;
  const int n0 = ng & 511;
  const float* W = (region == 0) ? Wq : (region == 1) ? Wk : Wv;
  float* out = qkv + (size_t)region * (NROWS * NDIM);

  const int tx = t & 15, ty = t >> 4;
  const int arow = t >> 2, akq = (t & 3) * 4;
  const int brow = t >> 4, bcol = (t & 15) * 4;

  float acc[4][4];
#pragma unroll
  for (int i = 0; i < 4; ++i)
#pragma unroll
    for (int j = 0; j < 4; ++j) acc[i][j] = 0.f;

  for (int k0 = 0; k0 < 512; k0 += 16) {
    float4 av = make_float4(0.f, 0.f, 0.f, 0.f);
    if (m0 + arow < NROWS)
      av = *(const float4*)&x[(size_t)(m0 + arow) * NDIM + k0 + akq];
    As[akq + 0][arow] = av.x; As[akq + 1][arow] = av.y;
    As[akq + 2][arow] = av.z; As[akq + 3][arow] = av.w;
    *(float4*)&Bs[brow][bcol] =
        *(const float4*)&W[(size_t)(k0 + brow) * NDIM + n0 + bcol];
    __syncthreads();
#pragma unroll
    for (int kk = 0; kk < 16; ++kk) {
      float4 a = *(const float4*)&As[kk][ty * 4];
      float4 b = *(const float4*)&Bs[kk][tx * 4];
      float aa[4] = {a.x, a.y, a.z, a.w};
      float bb[4] = {b.x, b.y, b.z, b.w};
#pragma unroll
      for (int i = 0; i < 4; ++i)
#pragma unroll
        for (int j = 0; j < 4; ++j) acc[i][j] = fmaf(aa[i], bb[j], acc[i][j]);
    }
    __syncthreads();
  }
#pragma unroll
  for (int i = 0; i < 4; ++i) {
    int row = m0 + ty * 4 + i;
    if (row < NROWS)
      *(float4*)&out[(size_t)row * NDIM + n0 + tx * 4] =
          make_float4(acc[i][0], acc[i][1], acc[i][2], acc[i][3]);
  }
}

// ---------------------------------------------------------------------------
// K2: S[h,b,i,j] = scale * q_i(h).k_j(h)  (j<272) ; U[h,b,i,f] = q_i(h).Wk_pe_f(h)
// grid: x = b*5+mt, y = nt (0..4 keys, 5..7 f), z = head. K=64, tile 64x64.
// All global loads coalesced (full cache lines).
// ---------------------------------------------------------------------------
__global__ __launch_bounds__(256) void su_gemm_k(
    const float* __restrict__ qb, const float* __restrict__ kb,
    const float* __restrict__ Wk,
    float* __restrict__ s_ws, short* __restrict__ u_ws)
{
  __shared__ float As[16][68];
  __shared__ float Bs[16][68];
  const int t = threadIdx.x;
  const int bx = blockIdx.x;
  const int b = bx / 5;
  const int m0 = (bx - b * 5) * 64;
  const int nt = blockIdx.y;
  const int h = blockIdx.z;
  const int n0 = nt * 64;

  const int tx = t & 15, ty = t >> 4;
  const int arow = t >> 2, akq = (t & 3) * 4;

  float acc[4][4];
#pragma unroll
  for (int i = 0; i < 4; ++i)
#pragma unroll
    for (int j = 0; j < 4; ++j) acc[i][j] = 0.f;

  for (int k0 = 0; k0 < 64; k0 += 16) {
    float4 av = make_float4(0.f, 0.f, 0.f, 0.f);
    {
      int i = m0 + arow;
      if (i < NL)
        av = *(const float4*)&qb[(size_t)(b * NL + i) * NDIM + h * DHEAD + k0 + akq];
    }
    As[akq + 0][arow] = av.x; As[akq + 1][arow] = av.y;
    As[akq + 2][arow] = av.z; As[akq + 3][arow] = av.w;
    float4 bv = make_float4(0.f, 0.f, 0.f, 0.f);
    if (nt < 5) {
      int j = n0 + arow;
      if (j < NL)
        bv = *(const float4*)&kb[(size_t)(b * NL + j) * NDIM + h * DHEAD + k0 + akq];
    } else {
      int f = n0 - 320 + arow;
      if (f < POSD)
        bv = *(const float4*)&Wk[(size_t)(512 + f) * NDIM + h * DHEAD + k0 + akq];
    }
    Bs[akq + 0][arow] = bv.x; Bs[akq + 1][arow] = bv.y;
    Bs[akq + 2][arow] = bv.z; Bs[akq + 3][arow] = bv.w;
    __syncthreads();
#pragma unroll
    for (int kk = 0; kk < 16; ++kk) {
      float4 a = *(const float4*)&As[kk][ty * 4];
      float4 b2 = *(const float4*)&Bs[kk][tx * 4];
      float aa[4] = {a.x, a.y, a.z, a.w};
      float bb[4] = {b2.x, b2.y, b2.z, b2.w};
#pragma unroll
      for (int i = 0; i < 4; ++i)
#pragma unroll
        for (int j = 0; j < 4; ++j) acc[i][j] = fmaf(aa[i], bb[j], acc[i][j]);
    }
    __syncthreads();
  }

  const size_t rowbase = (size_t)((h * NB + b) * SROWS + m0);
  if (nt < 5) {
#pragma unroll
    for (int ii = 0; ii < 4; ++ii) {
      size_t r = rowbase + ty * 4 + ii;
      *(float4*)&s_ws[r * SCOLS + n0 + tx * 4] =
          make_float4(acc[ii][0] * ATTN_SCALE, acc[ii][1] * ATTN_SCALE,
                      acc[ii][2] * ATTN_SCALE, acc[ii][3] * ATTN_SCALE);
    }
  } else {
#pragma unroll
    for (int ii = 0; ii < 4; ++ii) {
      size_t r = rowbase + ty * 4 + ii;
#pragma unroll
      for (int jj = 0; jj < 4; ++jj) {
        int f = n0 - 320 + tx * 4 + jj;
        if (f < POSD) u_ws[r * UCOLS + f] = bfb(acc[ii][jj]);
      }
    }
  }
}

// ---------------------------------------------------------------------------
// K5: out = attn_out @ Wo + bo
// ---------------------------------------------------------------------------
__global__ __launch_bounds__(256) void out_gemm_k(
    const float* __restrict__ A, const float* __restrict__ Wo,
    const float* __restrict__ bo, float* __restrict__ out)
{
  __shared__ float As[16][68];
  __shared__ float Bs[16][64];
  const int t  = threadIdx.x;
  const int m0 = blockIdx.x * 64;
  const int n0 = blockIdx.y * 64;

  const int tx = t & 15, ty = t >> 4;
  const int arow = t >> 2, akq = (t & 3) * 4;
  const int brow = t >> 4, bcol = (t & 15) * 4;

  float acc[4][4];
#pragma unroll
  for (int i = 0; i < 4; ++i)
#pragma unroll
    for (int j = 0; j < 4; ++j) acc[i][j] = 0.f;

  for (int k0 = 0; k0 < 512; k0 += 16) {
    float4 av = make_float4(0.f, 0.f, 0.f, 0.f);
    if (m0 + arow < NROWS)
      av = *(const float4*)&A[(size_t)(m0 + arow) * NDIM + k0 + akq];
    As[akq + 0][arow] = av.x; As[akq + 1][arow] = av.y;
    As[akq + 2][arow] = av.z; As[akq + 3][arow] = av.w;
    *(float4*)&Bs[brow][bcol] =
        *(const float4*)&Wo[(size_t)(k0 + brow) * NDIM + n0 + bcol];
    __syncthreads();
#pragma unroll
    for (int kk = 0; kk < 16; ++kk) {
      float4 a = *(const float4*)&As[kk][ty * 4];
      float4 b = *(const float4*)&Bs[kk][tx * 4];
      float aa[4] = {a.x, a.y, a.z, a.w};
      float bb[4] = {b.x, b.y, b.z, b.w};
#pragma unroll
      for (int i = 0; i < 4; ++i)
#pragma unroll
        for (int j = 0; j < 4; ++j) acc[i][j] = fmaf(aa[i], bb[j], acc[i][j]);
    }
    __syncthreads();
  }
  float4 bv = *(const float4*)&bo[n0 + tx * 4];
  float bb[4] = {bv.x, bv.y, bv.z, bv.w};
#pragma unroll
  for (int i = 0; i < 4; ++i) {
    int row = m0 + ty * 4 + i;
    if (row < NROWS)
      *(float4*)&out[(size_t)row * NDIM + n0 + tx * 4] =
          make_float4(acc[i][0] + bb[0], acc[i][1] + bb[1],
                      acc[i][2] + bb[2], acc[i][3] + bb[3]);
  }
}

// ---------------------------------------------------------------------------
// K3: pe attention. Block = (row, head-group hg, key-split ks). Reads
// precomputed S-base and U (all coalesced); adds pe logits via MFMA,
// online softmax, PV, w-accum MFMA, and this split's w @ Wv_pe projection.
// pe slot layout: 0..31 sin_r | 32..63 cos_r | 64..95 sin_t | 96..127 cos_t
//                 | 128 rc | 129 th | 130..159 zero
// Fragment maps (gfx950): A m=lane&15 k=(lane>>4)*8+j; B n=lane&15 same k;
// D col=lane&15 row=(lane>>4)*4+reg.
// ---------------------------------------------------------------------------
__global__ __launch_bounds__(256) void attn_pe_k(
    const float* __restrict__ s_ws, const short* __restrict__ u_ws,
    const float* __restrict__ vb, const float* __restrict__ pos,
    const float* __restrict__ Wv, const float* __restrict__ freqs,
    float* __restrict__ part)
{
  __shared__ short u_s[16 * USTR];
  __shared__ short p_bf[16 * PSTR];
  __shared__ float p_s[4][64];
  __shared__ float s_l[4][64];
  __shared__ float s_pe[4][64];
  __shared__ float w_s[4][160];
  __shared__ float rc_s[128], th_s[128];
  __shared__ float frp_s[NFREQ];
  __shared__ float m_s[4], l_s[4], fac_s[4];

  const int row = blockIdx.x;
  const int hg  = blockIdx.y;
  const int ks  = blockIdx.z;
  const int b = row / NL;
  const int i = row - b * NL;
  const bool spatial = (i < NLS);
  const int t = threadIdx.x;
  const int lane = t & 63;
  const int wv = t >> 6;
  const int g = lane >> 4;
  const int lr = lane & 15;
  const int hbase = hg * 4;
  const int h4 = t >> 6;
  const int dd = t & 63;

  for (int idx = t; idx < 16 * USTR / 2; idx += 256) ((int*)u_s)[idx] = 0;
  for (int idx = t; idx < 16 * PSTR / 2; idx += 256) ((int*)p_bf)[idx] = 0;
  if (t < NFREQ) frp_s[t] = freqs[t] * PI_F;
  if (t < 4) { m_s[t] = -1e30f; l_s[t] = 0.f; }
  __syncthreads();

  float px = 0.f, py = 0.f;
  if (spatial) {
    float2 pv = *(const float2*)&pos[(size_t)(b * NLS + i) * 2];
    px = pv.x; py = pv.y;
  }
  if (spatial && t < 128) {
    int key = ks * 128 + t;
    float2 kp = *(const float2*)&pos[(size_t)(b * NLS + key) * 2];
    float dx = kp.x - px, dy = kp.y - py;
    float r = sqrtf(dx * dx + dy * dy + 1e-8f);
    rc_s[t] = r / (PHYS_SCALE + r);
    th_s[t] = atan2f(dy, dx) * (1.0f / PI_F);
  }
  if (spatial) {
    for (int idx = t; idx < 4 * POSD; idx += 256) {
      int hh = idx / POSD, f = idx - hh * POSD;
      int slot = (f < 64) ? f : (f == 64) ? 128 : (f == 129) ? 129 : f - 1;
      u_s[hh * USTR + slot] =
          u_ws[((size_t)((hbase + hh) * NB + b) * SROWS + i) * UCOLS + f];
    }
  }
  __syncthreads();

  float oA = 0.f, oB = 0.f;
  f32x4 wacc[3];
#pragma unroll
  for (int q = 0; q < 3; ++q) wacc[q] = (f32x4){0.f, 0.f, 0.f, 0.f};

  for (int ti = 0; ti < 2; ++ti) {
    const int kloc = ks * 128 + ti * 64;   // key index 0..255
    const int koff = ti * 64;              // offset into rc_s/th_s

    // phase A: load base logits (coalesced) + pe logits via MFMA
    s_l[h4][dd] =
        s_ws[((size_t)((hbase + h4) * NB + b) * SROWS + i) * SCOLS + kloc + dd];
    if (spatial) {
      const int keyloc = koff + wv * 16 + lr;
      const float rc = rc_s[keyloc], th = th_s[keyloc];
      const float* frp = &frp_s[g * 8];
      s16x8 a0, a1, a2, a3, a4;
#pragma unroll
      for (int j = 0; j < 8; ++j) {
        float s1, c1, s2, c2;
        __sincosf(rc * frp[j], &s1, &c1);
        __sincosf(th * frp[j], &s2, &c2);
        a0[j] = bfb(s1); a1[j] = bfb(c1); a2[j] = bfb(s2); a3[j] = bfb(c2);
        a4[j] = 0;
      }
      if (g == 0) { a4[0] = bfb(rc); a4[1] = bfb(th); }
      const short* ur = &u_s[lr * USTR + g * 8];
      f32x4 acc = (f32x4){0.f, 0.f, 0.f, 0.f};
      acc = __builtin_amdgcn_mfma_f32_16x16x32_bf16(a0, *(const s16x8*)(ur), acc, 0, 0, 0);
      acc = __builtin_amdgcn_mfma_f32_16x16x32_bf16(a1, *(const s16x8*)(ur + 32), acc, 0, 0, 0);
      acc = __builtin_amdgcn_mfma_f32_16x16x32_bf16(a2, *(const s16x8*)(ur + 64), acc, 0, 0, 0);
      acc = __builtin_amdgcn_mfma_f32_16x16x32_bf16(a3, *(const s16x8*)(ur + 96), acc, 0, 0, 0);
      acc = __builtin_amdgcn_mfma_f32_16x16x32_bf16(a4, *(const s16x8*)(ur + 128), acc, 0, 0, 0);
      if (lr < 4) {
#pragma unroll
        for (int r = 0; r < 4; ++r)
          s_pe[lr][wv * 16 + g * 4 + r] = acc[r] * ATTN_SCALE;
      }
    }
    __syncthreads();

    // phase B: online softmax (wave per head)
    {
      float v = s_l[h4][dd];
      if (spatial) v += s_pe[h4][dd];
      float mx = v;
#pragma unroll
      for (int off = 32; off > 0; off >>= 1)
        mx = fmaxf(mx, __shfl_xor(mx, off, 64));
      float m_old = m_s[h4];
      float m_new = fmaxf(m_old, mx);
      float p = __expf(v - m_new);
      p_s[h4][dd] = p;
      p_bf[h4 * PSTR + dd] = bfb(p);
      float sum = p;
#pragma unroll
      for (int off = 32; off > 0; off >>= 1)
        sum += __shfl_xor(sum, off, 64);
      if (lane == 0) {
        float fac = __expf(m_old - m_new);
        m_s[h4] = m_new;
        l_s[h4] = l_s[h4] * fac + sum;
        fac_s[h4] = fac;
      }
    }
    __syncthreads();

    // phase C: PV + w-accum MFMA
    {
      float fac = fac_s[h4];
      oA *= fac; oB *= fac;
      const float* vbase = &vb[(size_t)(b * NL + kloc) * NDIM + (hbase + h4) * DHEAD + dd];
      const float* pp = p_s[h4];
#pragma unroll 8
      for (int j = 0; j < 64; j += 2) {
        oA = fmaf(pp[j], vbase[(size_t)j * NDIM], oA);
        oB = fmaf(pp[j + 1], vbase[(size_t)(j + 1) * NDIM], oB);
      }
    }
    if (spatial) {
      const float facw = fac_s[lr & 3];
#pragma unroll
      for (int q = 0; q < 3; ++q) {
        const int mc = wv + q * 4;
        if (mc < 10) {
#pragma unroll
          for (int r = 0; r < 4; ++r) wacc[q][r] *= facw;
          const int s = mc * 16 + lr;
          const float Fp = frp_s[s & 31];
          const bool useTh = (s >= 64 && s < 128) || (s == 129);
          const bool useCos = (s & 32) != 0;
#pragma unroll
          for (int kc = 0; kc < 2; ++kc) {
            s16x8 a;
#pragma unroll
            for (int jj = 0; jj < 8; ++jj) {
              const int j = koff + kc * 32 + g * 8 + jj;
              float x = useTh ? th_s[j] : rc_s[j];
              float v;
              if (s < 128) {
                float sn, cs;
                __sincosf(x * Fp, &sn, &cs);
                v = useCos ? cs : sn;
              } else {
                v = (s < 130) ? x : 0.f;
              }
              a[jj] = bfb(v);
            }
            const s16x8 pb = *(const s16x8*)&p_bf[lr * PSTR + kc * 32 + g * 8];
            wacc[q] = __builtin_amdgcn_mfma_f32_16x16x32_bf16(a, pb, wacc[q], 0, 0, 0);
          }
        }
      }
    }
    __syncthreads();
  }

  // ---- tail (ks==1): 16 global keys, no pe ----
  if (ks == 1) {
    if (t < 64) {
      const int hh = t >> 4, j = t & 15;
      s_l[hh][j] =
          s_ws[((size_t)((hbase + hh) * NB + b) * SROWS + i) * SCOLS + 256 + j];
    }
    __syncthreads();
    {
      float v = (dd < 16) ? s_l[h4][dd] : -1e30f;
      float mx = v;
#pragma unroll
      for (int off = 32; off > 0; off >>= 1)
        mx = fmaxf(mx, __shfl_xor(mx, off, 64));
      float m_old = m_s[h4];
      float m_new = fmaxf(m_old, mx);
      float p = (dd < 16) ? __expf(v - m_new) : 0.f;
      if (dd < 16) p_s[h4][dd] = p;
      float sum = p;
#pragma unroll
      for (int off = 32; off > 0; off >>= 1)
        sum += __shfl_xor(sum, off, 64);
      if (lane == 0) {
        float fac = __expf(m_old - m_new);
        m_s[h4] = m_new;
        l_s[h4] = l_s[h4] * fac + sum;
        fac_s[h4] = fac;
      }
    }
    __syncthreads();
    {
      float fac = fac_s[h4];
      oA *= fac; oB *= fac;
      const float* vbase = &vb[(size_t)(b * NL + 256) * NDIM + (hbase + h4) * DHEAD + dd];
      const float* pp = p_s[h4];
#pragma unroll 4
      for (int j = 0; j < 16; j += 2) {
        oA = fmaf(pp[j], vbase[(size_t)j * NDIM], oA);
        oB = fmaf(pp[j + 1], vbase[(size_t)(j + 1) * NDIM], oB);
      }
    }
    if (spatial) {
      const float facw = fac_s[lr & 3];
#pragma unroll
      for (int q = 0; q < 3; ++q)
#pragma unroll
        for (int r = 0; r < 4; ++r) wacc[q][r] *= facw;
    }
  }

  // ---- epilogue: gather w, project with Wv_pe, write partial ----
  __syncthreads();
  if (spatial && lr < 4) {
#pragma unroll
    for (int q = 0; q < 3; ++q) {
      const int mc = wv + q * 4;
      if (mc < 10) {
#pragma unroll
        for (int r = 0; r < 4; ++r)
          w_s[lr][mc * 16 + g * 4 + r] = wacc[q][r];
      }
    }
  }
  __syncthreads();

  float o = oA + oB;
  if (spatial) {
    const float* wsr = w_s[h4];
    const float* wvb = &Wv[(size_t)512 * NDIM + (hbase + h4) * DHEAD + dd];
    float e0 = 0.f, e1 = 0.f;
#pragma unroll 4
    for (int sf = 0; sf < 64; sf += 2) {
      e0 = fmaf(wsr[sf], wvb[(size_t)sf * NDIM], e0);
      e1 = fmaf(wsr[sf + 1], wvb[(size_t)(sf + 1) * NDIM], e1);
    }
#pragma unroll 4
    for (int sf = 64; sf < 128; sf += 2) {
      e0 = fmaf(wsr[sf], wvb[(size_t)(sf + 1) * NDIM], e0);
      e1 = fmaf(wsr[sf + 1], wvb[(size_t)(sf + 2) * NDIM], e1);
    }
    e0 = fmaf(wsr[128], wvb[(size_t)64 * NDIM], e0);
    e1 = fmaf(wsr[129], wvb[(size_t)129 * NDIM], e1);
    o += e0 + e1;
  }
  float* prow = part + ((size_t)(ks * NROWS + row) * 2 + hg) * PART_STRIDE;
  prow[t] = o;
  if (t < 4) { prow[256 + t] = m_s[t]; prow[260 + t] = l_s[t]; }
}

// ---------------------------------------------------------------------------
// K4: combine 2 key-split partials per (row, head-group)
// ---------------------------------------------------------------------------
__global__ __launch_bounds__(256) void combine_k(
    const float* __restrict__ part, float* __restrict__ ao)
{
  const int row = blockIdx.x;
  const int hg = blockIdx.y;
  const int t = threadIdx.x;
  const int h4 = t >> 6;

  const float* p0 = part + ((size_t)(0 * NROWS + row) * 2 + hg) * PART_STRIDE;
  const float* p1 = part + ((size_t)(1 * NROWS + row) * 2 + hg) * PART_STRIDE;
  float m0 = p0[256 + h4], m1 = p1[256 + h4];
  float M = fmaxf(m0, m1);
  float f0 = __expf(m0 - M), f1 = __expf(m1 - M);
  float L = p0[260 + h4] * f0 + p1[260 + h4] * f1;
  ao[(size_t)row * NDIM + hg * 256 + t] = (p0[t] * f0 + p1[t] * f1) / L;
}

// ---------------------------------------------------------------------------
extern "C" void kernel_launch(void* const* d_in, const int* in_sizes, int n_in,
                              void* d_out, int out_size, void* d_ws, size_t ws_size,
                              hipStream_t stream)
{
  (void)in_sizes; (void)n_in; (void)out_size; (void)ws_size;
  const float* x     = (const float*)d_in[0];
  const float* pos   = (const float*)d_in[1];
  const float* Wq    = (const float*)d_in[2];
  const float* Wk    = (const float*)d_in[3];
  const float* Wv    = (const float*)d_in[4];
  const float* Wo    = (const float*)d_in[5];
  const float* bo    = (const float*)d_in[6];
  const float* freqs = (const float*)d_in[7];

  float* ws = (float*)d_ws;
  float* qkv  = ws;                                      // [3][544][512]
  float* qb   = qkv;
  float* kb   = qkv + (size_t)NROWS * NDIM;
  float* vb   = qkv + (size_t)2 * NROWS * NDIM;
  float* ao   = qkv + (size_t)3 * NROWS * NDIM;          // [544][512]
  float* part = ao  + (size_t)NROWS * NDIM;              // [2][544][2][264]
  float* s_ws = part + (size_t)2 * NROWS * 2 * PART_STRIDE;  // [8][2][320][320]
  short* u_ws = (short*)(s_ws + (size_t)NHEADS * NB * SROWS * SCOLS); // [8][2][320][132] bf16

  qkv_gemm_k<<<dim3(9, 24), 256, 0, stream>>>(x, Wq, Wk, Wv, qkv);
  su_gemm_k<<<dim3(10, 8, 8), 256, 0, stream>>>(qb, kb, Wk, s_ws, u_ws);
  attn_pe_k<<<dim3(NROWS, 2, 2), 256, 0, stream>>>(s_ws, u_ws, vb, pos, Wv, freqs, part);
  combine_k<<<dim3(NROWS, 2), 256, 0, stream>>>(part, ao);
  out_gemm_k<<<dim3(9, 8), 256, 0, stream>>>(ao, Wo, bo, (float*)d_out);
}

// Round 24
// 119.803 us; speedup vs baseline: 1.5474x; 1.0371x over previous
//
#include <hip/hip_runtime.h>
#include <math.h>

#define NHEADS 8
#define DHEAD 64
#define NDIM 512
#define NFREQ 32
#define POSD 130           // 2*(32*2+1)
#define NB 2
#define NL 272
#define NLS 256
#define NROWS (NB*NL)      // 544
#define ATTN_SCALE 0.125f
#define PHYS_SCALE 51.5f
#define PI_F 3.14159265358979323846f
#define USTR 168           // u_s row stride (shorts)
#define PSTR 72            // p_bf row stride (shorts)
#define PESTR 168          // pe_lds row stride (shorts), 336B: 16B-aligned
#define PART_STRIDE 264    // 256 o + 4 m + 4 l
#define SROWS 320          // padded rows per (head,batch)
#define SCOLS 320          // padded key cols
#define UCOLS 132

typedef short s16x8 __attribute__((ext_vector_type(8)));
typedef float f32x4 __attribute__((ext_vector_type(4)));

__device__ __forceinline__ short bfb(float x) {
  unsigned short u = __builtin_bit_cast(unsigned short, (__bf16)x);
  return (short)u;
}

// ---------------------------------------------------------------------------
// K1: qkv = x @ [Wq | Wk[:512] | Wv[:512]]   (M=544, N=1536, K=512, fp32)
// ---------------------------------------------------------------------------
__global__ __launch_bounds__(256) void qkv_gemm_k(
    const float* __restrict__ x,
    const float* __restrict__ Wq, const float* __restrict__ Wk,
    const float* __restrict__ Wv,
    float* __restrict__ qkv)
{
  __shared__ float As[16][68];
  __shared__ float Bs[16][64];
  const int t  = threadIdx.x;
  const int m0 = blockIdx.x * 64;
  const int ng = blockIdx.y * 64;
  const int region = ng >> 9;
  const int n0 = ng & 511;
  const float* W = (region == 0) ? Wq : (region == 1) ? Wk : Wv;
  float* out = qkv + (size_t)region * (NROWS * NDIM);

  const int tx = t & 15, ty = t >> 4;
  const int arow = t >> 2, akq = (t & 3) * 4;
  const int brow = t >> 4, bcol = (t & 15) * 4;

  float acc[4][4];
#pragma unroll
  for (int i = 0; i < 4; ++i)
#pragma unroll
    for (int j = 0; j < 4; ++j) acc[i][j] = 0.f;

  for (int k0 = 0; k0 < 512; k0 += 16) {
    float4 av = make_float4(0.f, 0.f, 0.f, 0.f);
    if (m0 + arow < NROWS)
      av = *(const float4*)&x[(size_t)(m0 + arow) * NDIM + k0 + akq];
    As[akq + 0][arow] = av.x; As[akq + 1][arow] = av.y;
    As[akq + 2][arow] = av.z; As[akq + 3][arow] = av.w;
    *(float4*)&Bs[brow][bcol] =
        *(const float4*)&W[(size_t)(k0 + brow) * NDIM + n0 + bcol];
    __syncthreads();
#pragma unroll
    for (int kk = 0; kk < 16; ++kk) {
      float4 a = *(const float4*)&As[kk][ty * 4];
      float4 b = *(const float4*)&Bs[kk][tx * 4];
      float aa[4] = {a.x, a.y, a.z, a.w};
      float bb[4] = {b.x, b.y, b.z, b.w};
#pragma unroll
      for (int i = 0; i < 4; ++i)
#pragma unroll
        for (int j = 0; j < 4; ++j) acc[i][j] = fmaf(aa[i], bb[j], acc[i][j]);
    }
    __syncthreads();
  }
#pragma unroll
  for (int i = 0; i < 4; ++i) {
    int row = m0 + ty * 4 + i;
    if (row < NROWS)
      *(float4*)&out[(size_t)row * NDIM + n0 + tx * 4] =
          make_float4(acc[i][0], acc[i][1], acc[i][2], acc[i][3]);
  }
}

// ---------------------------------------------------------------------------
// K2: S[h,b,i,j] = scale * q_i(h).k_j(h)  (j<272) ; U[h,b,i,f] = q_i(h).Wk_pe_f(h)
// grid: x = b*5+mt, y = nt (0..4 keys, 5..7 f), z = head. K=64, tile 64x64.
// ---------------------------------------------------------------------------
__global__ __launch_bounds__(256) void su_gemm_k(
    const float* __restrict__ qb, const float* __restrict__ kb,
    const float* __restrict__ Wk,
    float* __restrict__ s_ws, short* __restrict__ u_ws)
{
  __shared__ float As[16][68];
  __shared__ float Bs[16][68];
  const int t = threadIdx.x;
  const int bx = blockIdx.x;
  const int b = bx / 5;
  const int m0 = (bx - b * 5) * 64;
  const int nt = blockIdx.y;
  const int h = blockIdx.z;
  const int n0 = nt * 64;

  const int tx = t & 15, ty = t >> 4;
  const int arow = t >> 2, akq = (t & 3) * 4;

  float acc[4][4];
#pragma unroll
  for (int i = 0; i < 4; ++i)
#pragma unroll
    for (int j = 0; j < 4; ++j) acc[i][j] = 0.f;

  for (int k0 = 0; k0 < 64; k0 += 16) {
    float4 av = make_float4(0.f, 0.f, 0.f, 0.f);
    {
      int i = m0 + arow;
      if (i < NL)
        av = *(const float4*)&qb[(size_t)(b * NL + i) * NDIM + h * DHEAD + k0 + akq];
    }
    As[akq + 0][arow] = av.x; As[akq + 1][arow] = av.y;
    As[akq + 2][arow] = av.z; As[akq + 3][arow] = av.w;
    float4 bv = make_float4(0.f, 0.f, 0.f, 0.f);
    if (nt < 5) {
      int j = n0 + arow;
      if (j < NL)
        bv = *(const float4*)&kb[(size_t)(b * NL + j) * NDIM + h * DHEAD + k0 + akq];
    } else {
      int f = n0 - 320 + arow;
      if (f < POSD)
        bv = *(const float4*)&Wk[(size_t)(512 + f) * NDIM + h * DHEAD + k0 + akq];
    }
    Bs[akq + 0][arow] = bv.x; Bs[akq + 1][arow] = bv.y;
    Bs[akq + 2][arow] = bv.z; Bs[akq + 3][arow] = bv.w;
    __syncthreads();
#pragma unroll
    for (int kk = 0; kk < 16; ++kk) {
      float4 a = *(const float4*)&As[kk][ty * 4];
      float4 b2 = *(const float4*)&Bs[kk][tx * 4];
      float aa[4] = {a.x, a.y, a.z, a.w};
      float bb[4] = {b2.x, b2.y, b2.z, b2.w};
#pragma unroll
      for (int i = 0; i < 4; ++i)
#pragma unroll
        for (int j = 0; j < 4; ++j) acc[i][j] = fmaf(aa[i], bb[j], acc[i][j]);
    }
    __syncthreads();
  }

  const size_t rowbase = (size_t)((h * NB + b) * SROWS + m0);
  if (nt < 5) {
#pragma unroll
    for (int ii = 0; ii < 4; ++ii) {
      size_t r = rowbase + ty * 4 + ii;
      *(float4*)&s_ws[r * SCOLS + n0 + tx * 4] =
          make_float4(acc[ii][0] * ATTN_SCALE, acc[ii][1] * ATTN_SCALE,
                      acc[ii][2] * ATTN_SCALE, acc[ii][3] * ATTN_SCALE);
    }
  } else {
#pragma unroll
    for (int ii = 0; ii < 4; ++ii) {
      size_t r = rowbase + ty * 4 + ii;
#pragma unroll
      for (int jj = 0; jj < 4; ++jj) {
        int f = n0 - 320 + tx * 4 + jj;
        if (f < POSD) u_ws[r * UCOLS + f] = bfb(acc[ii][jj]);
      }
    }
  }
}

// ---------------------------------------------------------------------------
// K5: out = attn_out @ Wo + bo
// ---------------------------------------------------------------------------
__global__ __launch_bounds__(256) void out_gemm_k(
    const float* __restrict__ A, const float* __restrict__ Wo,
    const float* __restrict__ bo, float* __restrict__ out)
{
  __shared__ float As[16][68];
  __shared__ float Bs[16][64];
  const int t  = threadIdx.x;
  const int m0 = blockIdx.x * 64;
  const int n0 = blockIdx.y * 64;

  const int tx = t & 15, ty = t >> 4;
  const int arow = t >> 2, akq = (t & 3) * 4;
  const int brow = t >> 4, bcol = (t & 15) * 4;

  float acc[4][4];
#pragma unroll
  for (int i = 0; i < 4; ++i)
#pragma unroll
    for (int j = 0; j < 4; ++j) acc[i][j] = 0.f;

  for (int k0 = 0; k0 < 512; k0 += 16) {
    float4 av = make_float4(0.f, 0.f, 0.f, 0.f);
    if (m0 + arow < NROWS)
      av = *(const float4*)&A[(size_t)(m0 + arow) * NDIM + k0 + akq];
    As[akq + 0][arow] = av.x; As[akq + 1][arow] = av.y;
    As[akq + 2][arow] = av.z; As[akq + 3][arow] = av.w;
    *(float4*)&Bs[brow][bcol] =
        *(const float4*)&Wo[(size_t)(k0 + brow) * NDIM + n0 + bcol];
    __syncthreads();
#pragma unroll
    for (int kk = 0; kk < 16; ++kk) {
      float4 a = *(const float4*)&As[kk][ty * 4];
      float4 b = *(const float4*)&Bs[kk][tx * 4];
      float aa[4] = {a.x, a.y, a.z, a.w};
      float bb[4] = {b.x, b.y, b.z, b.w};
#pragma unroll
      for (int i = 0; i < 4; ++i)
#pragma unroll
        for (int j = 0; j < 4; ++j) acc[i][j] = fmaf(aa[i], bb[j], acc[i][j]);
    }
    __syncthreads();
  }
  float4 bv = *(const float4*)&bo[n0 + tx * 4];
  float bb[4] = {bv.x, bv.y, bv.z, bv.w};
#pragma unroll
  for (int i = 0; i < 4; ++i) {
    int row = m0 + ty * 4 + i;
    if (row < NROWS)
      *(float4*)&out[(size_t)row * NDIM + n0 + tx * 4] =
          make_float4(acc[i][0] + bb[0], acc[i][1] + bb[1],
                      acc[i][2] + bb[2], acc[i][3] + bb[3]);
  }
}

// ---------------------------------------------------------------------------
// K3: pe attention. Block = (row, head-group hg, key-split ks).
// Phase A computes the full 64x160 pe tile (bf16) via 4 sincos + rotation
// recurrence per lane, stores it in pe_lds, and does the pe-logit MFMA.
// Phase C re-reads pe_lds (transposed) for the w-accum MFMA: zero sincos.
// pe slot layout: 0..31 sin_r | 32..63 cos_r | 64..95 sin_t | 96..127 cos_t
//                 | 128 rc | 129 th | 130..159 zero
// Fragment maps (gfx950): A m=lane&15 k=(lane>>4)*8+j; B n=lane&15 same k;
// D col=lane&15 row=(lane>>4)*4+reg.
// ---------------------------------------------------------------------------
__global__ __launch_bounds__(256) void attn_pe_k(
    const float* __restrict__ s_ws, const short* __restrict__ u_ws,
    const float* __restrict__ vb, const float* __restrict__ pos,
    const float* __restrict__ Wv, const float* __restrict__ freqs,
    float* __restrict__ part)
{
  __shared__ short u_s[16 * USTR];
  __shared__ short p_bf[16 * PSTR];
  __shared__ short pe_lds[64 * PESTR];
  __shared__ float p_s[4][64];
  __shared__ float s_l[4][64];
  __shared__ float s_pe[4][64];
  __shared__ float w_s[4][160];
  __shared__ float rc_s[128], th_s[128];
  __shared__ float frp_s[NFREQ];
  __shared__ float m_s[4], l_s[4], fac_s[4];

  const int row = blockIdx.x;
  const int hg  = blockIdx.y;
  const int ks  = blockIdx.z;
  const int b = row / NL;
  const int i = row - b * NL;
  const bool spatial = (i < NLS);
  const int t = threadIdx.x;
  const int lane = t & 63;
  const int wv = t >> 6;
  const int g = lane >> 4;
  const int lr = lane & 15;
  const int hbase = hg * 4;
  const int h4 = t >> 6;
  const int dd = t & 63;

  for (int idx = t; idx < 16 * USTR / 2; idx += 256) ((int*)u_s)[idx] = 0;
  for (int idx = t; idx < 16 * PSTR / 2; idx += 256) ((int*)p_bf)[idx] = 0;
  if (t < NFREQ) frp_s[t] = freqs[t] * PI_F;
  if (t < 4) { m_s[t] = -1e30f; l_s[t] = 0.f; }
  __syncthreads();

  float px = 0.f, py = 0.f;
  if (spatial) {
    float2 pv = *(const float2*)&pos[(size_t)(b * NLS + i) * 2];
    px = pv.x; py = pv.y;
  }
  if (spatial && t < 128) {
    int key = ks * 128 + t;
    float2 kp = *(const float2*)&pos[(size_t)(b * NLS + key) * 2];
    float dx = kp.x - px, dy = kp.y - py;
    float r = sqrtf(dx * dx + dy * dy + 1e-8f);
    rc_s[t] = r / (PHYS_SCALE + r);
    th_s[t] = atan2f(dy, dx) * (1.0f / PI_F);
  }
  if (spatial) {
    for (int idx = t; idx < 4 * POSD; idx += 256) {
      int hh = idx / POSD, f = idx - hh * POSD;
      int slot = (f < 64) ? f : (f == 64) ? 128 : (f == 129) ? 129 : f - 1;
      u_s[hh * USTR + slot] =
          u_ws[((size_t)((hbase + hh) * NB + b) * SROWS + i) * UCOLS + f];
    }
  }
  __syncthreads();

  float oA = 0.f, oB = 0.f;
  f32x4 wacc[3];
#pragma unroll
  for (int q = 0; q < 3; ++q) wacc[q] = (f32x4){0.f, 0.f, 0.f, 0.f};

  for (int ti = 0; ti < 2; ++ti) {
    const int kloc = ks * 128 + ti * 64;   // key index 0..255
    const int koff = ti * 64;              // offset into rc_s/th_s

    // phase A: load base logits (coalesced) + build pe tile (recurrence) +
    //          pe-logit MFMA + store pe tile to LDS
    s_l[h4][dd] =
        s_ws[((size_t)((hbase + h4) * NB + b) * SROWS + i) * SCOLS + kloc + dd];
    if (spatial) {
      const int krow = wv * 16 + lr;       // local key 0..63
      const float rc = rc_s[koff + krow], th = th_s[koff + krow];
      const float f0 = frp_s[g * 8];
      const float dphi = frp_s[1] - frp_s[0];
      float sr, cr, st_, ct_;
      __sincosf(rc * f0, &sr, &cr);
      __sincosf(th * f0, &st_, &ct_);
      float srd, crd, std_, ctd;
      __sincosf(rc * dphi, &srd, &crd);
      __sincosf(th * dphi, &std_, &ctd);
      s16x8 a0, a1, a2, a3, a4;
#pragma unroll
      for (int j = 0; j < 8; ++j) {
        a0[j] = bfb(sr); a1[j] = bfb(cr); a2[j] = bfb(st_); a3[j] = bfb(ct_);
        a4[j] = 0;
        float nsr = fmaf(sr, crd, cr * srd);
        float ncr = fmaf(cr, crd, -sr * srd);
        sr = nsr; cr = ncr;
        float nst = fmaf(st_, ctd, ct_ * std_);
        float nct = fmaf(ct_, ctd, -st_ * std_);
        st_ = nst; ct_ = nct;
      }
      if (g == 0) { a4[0] = bfb(rc); a4[1] = bfb(th); }
      // store pe tile (row krow, 5 slot groups of 8)
      {
        short* pr = &pe_lds[krow * PESTR];
        *(s16x8*)&pr[g * 8]       = a0;
        *(s16x8*)&pr[32 + g * 8]  = a1;
        *(s16x8*)&pr[64 + g * 8]  = a2;
        *(s16x8*)&pr[96 + g * 8]  = a3;
        *(s16x8*)&pr[128 + g * 8] = a4;
      }
      const short* ur = &u_s[lr * USTR + g * 8];
      f32x4 acc = (f32x4){0.f, 0.f, 0.f, 0.f};
      acc = __builtin_amdgcn_mfma_f32_16x16x32_bf16(a0, *(const s16x8*)(ur), acc, 0, 0, 0);
      acc = __builtin_amdgcn_mfma_f32_16x16x32_bf16(a1, *(const s16x8*)(ur + 32), acc, 0, 0, 0);
      acc = __builtin_amdgcn_mfma_f32_16x16x32_bf16(a2, *(const s16x8*)(ur + 64), acc, 0, 0, 0);
      acc = __builtin_amdgcn_mfma_f32_16x16x32_bf16(a3, *(const s16x8*)(ur + 96), acc, 0, 0, 0);
      acc = __builtin_amdgcn_mfma_f32_16x16x32_bf16(a4, *(const s16x8*)(ur + 128), acc, 0, 0, 0);
      if (lr < 4) {
#pragma unroll
        for (int r = 0; r < 4; ++r)
          s_pe[lr][wv * 16 + g * 4 + r] = acc[r] * ATTN_SCALE;
      }
    }
    __syncthreads();

    // phase B: online softmax (wave per head)
    {
      float v = s_l[h4][dd];
      if (spatial) v += s_pe[h4][dd];
      float mx = v;
#pragma unroll
      for (int off = 32; off > 0; off >>= 1)
        mx = fmaxf(mx, __shfl_xor(mx, off, 64));
      float m_old = m_s[h4];
      float m_new = fmaxf(m_old, mx);
      float p = __expf(v - m_new);
      p_s[h4][dd] = p;
      p_bf[h4 * PSTR + dd] = bfb(p);
      float sum = p;
#pragma unroll
      for (int off = 32; off > 0; off >>= 1)
        sum += __shfl_xor(sum, off, 64);
      if (lane == 0) {
        float fac = __expf(m_old - m_new);
        m_s[h4] = m_new;
        l_s[h4] = l_s[h4] * fac + sum;
        fac_s[h4] = fac;
      }
    }
    __syncthreads();

    // phase C: PV + w-accum MFMA (pe read back from LDS, transposed)
    {
      float fac = fac_s[h4];
      oA *= fac; oB *= fac;
      const float* vbase = &vb[(size_t)(b * NL + kloc) * NDIM + (hbase + h4) * DHEAD + dd];
      const float* pp = p_s[h4];
#pragma unroll 8
      for (int j = 0; j < 64; j += 2) {
        oA = fmaf(pp[j], vbase[(size_t)j * NDIM], oA);
        oB = fmaf(pp[j + 1], vbase[(size_t)(j + 1) * NDIM], oB);
      }
    }
    if (spatial) {
      const float facw = fac_s[lr & 3];
#pragma unroll
      for (int q = 0; q < 3; ++q) {
        const int mc = wv + q * 4;
        if (mc < 10) {
#pragma unroll
          for (int r = 0; r < 4; ++r) wacc[q][r] *= facw;
          const int s = mc * 16 + lr;            // slot 0..159
#pragma unroll
          for (int kc = 0; kc < 2; ++kc) {
            s16x8 a;
#pragma unroll
            for (int jj = 0; jj < 8; ++jj) {
              const int j = kc * 32 + g * 8 + jj;  // local key 0..63
              a[jj] = pe_lds[j * PESTR + s];
            }
            const s16x8 pb = *(const s16x8*)&p_bf[lr * PSTR + kc * 32 + g * 8];
            wacc[q] = __builtin_amdgcn_mfma_f32_16x16x32_bf16(a, pb, wacc[q], 0, 0, 0);
          }
        }
      }
    }
    __syncthreads();
  }

  // ---- tail (ks==1): 16 global keys, no pe ----
  if (ks == 1) {
    if (t < 64) {
      const int hh = t >> 4, j = t & 15;
      s_l[hh][j] =
          s_ws[((size_t)((hbase + hh) * NB + b) * SROWS + i) * SCOLS + 256 + j];
    }
    __syncthreads();
    {
      float v = (dd < 16) ? s_l[h4][dd] : -1e30f;
      float mx = v;
#pragma unroll
      for (int off = 32; off > 0; off >>= 1)
        mx = fmaxf(mx, __shfl_xor(mx, off, 64));
      float m_old = m_s[h4];
      float m_new = fmaxf(m_old, mx);
      float p = (dd < 16) ? __expf(v - m_new) : 0.f;
      if (dd < 16) p_s[h4][dd] = p;
      float sum = p;
#pragma unroll
      for (int off = 32; off > 0; off >>= 1)
        sum += __shfl_xor(sum, off, 64);
      if (lane == 0) {
        float fac = __expf(m_old - m_new);
        m_s[h4] = m_new;
        l_s[h4] = l_s[h4] * fac + sum;
        fac_s[h4] = fac;
      }
    }
    __syncthreads();
    {
      float fac = fac_s[h4];
      oA *= fac; oB *= fac;
      const float* vbase = &vb[(size_t)(b * NL + 256) * NDIM + (hbase + h4) * DHEAD + dd];
      const float* pp = p_s[h4];
#pragma unroll 4
      for (int j = 0; j < 16; j += 2) {
        oA = fmaf(pp[j], vbase[(size_t)j * NDIM], oA);
        oB = fmaf(pp[j + 1], vbase[(size_t)(j + 1) * NDIM], oB);
      }
    }
    if (spatial) {
      const float facw = fac_s[lr & 3];
#pragma unroll
      for (int q = 0; q < 3; ++q)
#pragma unroll
        for (int r = 0; r < 4; ++r) wacc[q][r] *= facw;
    }
  }

  // ---- epilogue: gather w, project with Wv_pe, write partial ----
  __syncthreads();
  if (spatial && lr < 4) {
#pragma unroll
    for (int q = 0; q < 3; ++q) {
      const int mc = wv + q * 4;
      if (mc < 10) {
#pragma unroll
        for (int r = 0; r < 4; ++r)
          w_s[lr][mc * 16 + g * 4 + r] = wacc[q][r];
      }
    }
  }
  __syncthreads();

  float o = oA + oB;
  if (spatial) {
    const float* wsr = w_s[h4];
    const float* wvb = &Wv[(size_t)512 * NDIM + (hbase + h4) * DHEAD + dd];
    float e0 = 0.f, e1 = 0.f;
#pragma unroll 4
    for (int sf = 0; sf < 64; sf += 2) {
      e0 = fmaf(wsr[sf], wvb[(size_t)sf * NDIM], e0);
      e1 = fmaf(wsr[sf + 1], wvb[(size_t)(sf + 1) * NDIM], e1);
    }
#pragma unroll 4
    for (int sf = 64; sf < 128; sf += 2) {
      e0 = fmaf(wsr[sf], wvb[(size_t)(sf + 1) * NDIM], e0);
      e1 = fmaf(wsr[sf + 1], wvb[(size_t)(sf + 2) * NDIM], e1);
    }
    e0 = fmaf(wsr[128], wvb[(size_t)64 * NDIM], e0);
    e1 = fmaf(wsr[129], wvb[(size_t)129 * NDIM], e1);
    o += e0 + e1;
  }
  float* prow = part + ((size_t)(ks * NROWS + row) * 2 + hg) * PART_STRIDE;
  prow[t] = o;
  if (t < 4) { prow[256 + t] = m_s[t]; prow[260 + t] = l_s[t]; }
}

// ---------------------------------------------------------------------------
// K4: combine 2 key-split partials per (row, head-group)
// ---------------------------------------------------------------------------
__global__ __launch_bounds__(256) void combine_k(
    const float* __restrict__ part, float* __restrict__ ao)
{
  const int row = blockIdx.x;
  const int hg = blockIdx.y;
  const int t = threadIdx.x;
  const int h4 = t >> 6;

  const float* p0 = part + ((size_t)(0 * NROWS + row) * 2 + hg) * PART_STRIDE;
  const float* p1 = part + ((size_t)(1 * NROWS + row) * 2 + hg) * PART_STRIDE;
  float m0 = p0[256 + h4], m1 = p1[256 + h4];
  float M = fmaxf(m0, m1);
  float f0 = __expf(m0 - M), f1 = __expf(m1 - M);
  float L = p0[260 + h4] * f0 + p1[260 + h4] * f1;
  ao[(size_t)row * NDIM + hg * 256 + t] = (p0[t] * f0 + p1[t] * f1) / L;
}

// ---------------------------------------------------------------------------
extern "C" void kernel_launch(void* const* d_in, const int* in_sizes, int n_in,
                              void* d_out, int out_size, void* d_ws, size_t ws_size,
                              hipStream_t stream)
{
  (void)in_sizes; (void)n_in; (void)out_size; (void)ws_size;
  const float* x     = (const float*)d_in[0];
  const float* pos   = (const float*)d_in[1];
  const float* Wq    = (const float*)d_in[2];
  const float* Wk    = (const float*)d_in[3];
  const float* Wv    = (const float*)d_in[4];
  const float* Wo    = (const float*)d_in[5];
  const float* bo    = (const float*)d_in[6];
  const float* freqs = (const float*)d_in[7];

  float* ws = (float*)d_ws;
  float* qkv  = ws;                                      // [3][544][512]
  float* qb   = qkv;
  float* kb   = qkv + (size_t)NROWS * NDIM;
  float* vb   = qkv + (size_t)2 * NROWS * NDIM;
  float* ao   = qkv + (size_t)3 * NROWS * NDIM;          // [544][512]
  float* part = ao  + (size_t)NROWS * NDIM;              // [2][544][2][264]
  float* s_ws = part + (size_t)2 * NROWS * 2 * PART_STRIDE;  // [8][2][320][320]
  short* u_ws = (short*)(s_ws + (size_t)NHEADS * NB * SROWS * SCOLS); // [8][2][320][132] bf16

  qkv_gemm_k<<<dim3(9, 24), 256, 0, stream>>>(x, Wq, Wk, Wv, qkv);
  su_gemm_k<<<dim3(10, 8, 8), 256, 0, stream>>>(qb, kb, Wk, s_ws, u_ws);
  attn_pe_k<<<dim3(NROWS, 2, 2), 256, 0, stream>>>(s_ws, u_ws, vb, pos, Wv, freqs, part);
  combine_k<<<dim3(NROWS, 2), 256, 0, stream>>>(part, ao);
  out_gemm_k<<<dim3(9, 8), 256, 0, stream>>>(ao, Wo, bo, (float*)d_out);
}